// Round 1
// baseline (213.016 us; speedup 1.0000x reference)
//
#include <hip/hip_runtime.h>

// Fused causal MHA on gfx950.  Pipeline:
//   k_convert:      x fp32 -> xb bf16                       [4096][768]
//   k_transpose_w:  W_Q/K/V fp32 [h][768][64] -> bf16 [h][64][768]  (= B^T rows n=h*64+k)
//                   W_O  fp32 [768][768]      -> bf16 [768][768]^T  (rows m, cols f=h*64+d)
//   k_gemm<true>:   qb/kb/vb bf16 = xb @ W^T + bias          (MFMA 16x16x32 bf16)
//   k_transpose_v:  vb -> vtb [b*12+h][64][2048]  (V^T per head)
//   k_flash:        online-softmax flash attention -> zb bf16
//   k_gemm<false>:  d_out fp32 = zb @ Wo^T + b_O
//
// ws layout (bytes): xb/zb 0..6291456 | qb 6291456 | kb 12582912 | vb 18874368
//   vtb 25165824 | wqT 31457280 | wkT 32636928 | wvT 33816576 | woT 34996224
//   total 36175872 B.

#define DEVINL __device__ __forceinline__

using bf16x8 = __attribute__((ext_vector_type(8))) __bf16;
using f32x4  = __attribute__((ext_vector_type(4))) float;

DEVINL unsigned short f32_bf16(float f) {
    unsigned u = __builtin_bit_cast(unsigned, f);
    return (unsigned short)((u + 0x7FFFu + ((u >> 16) & 1u)) >> 16);
}

// ---------------- convert fp32 -> bf16, 4 elems/thread ----------------
__global__ __launch_bounds__(256) void k_convert(const float* __restrict__ in,
                                                 unsigned short* __restrict__ out) {
    int i = (blockIdx.x * 256 + threadIdx.x) * 4;
    float4 v = *(const float4*)(in + i);
    ushort4 o;
    o.x = f32_bf16(v.x); o.y = f32_bf16(v.y); o.z = f32_bf16(v.z); o.w = f32_bf16(v.w);
    *(ushort4*)(out + i) = o;
}

// ---------------- transpose + convert: in fp32 [R][C] -> out bf16 [C][R], batched ----
__global__ __launch_bounds__(256) void k_transpose_w(const float* __restrict__ in,
                                                     unsigned short* __restrict__ out,
                                                     int R, int C, int tilesR) {
    __shared__ unsigned short tl[64][68];
    const int batch = blockIdx.y;
    const int tr = blockIdx.x % tilesR, tc = blockIdx.x / tilesR;
    in  += (size_t)batch * R * C;
    out += (size_t)batch * R * C;
    const int t = threadIdx.x, c = t & 63, r0 = t >> 6;
#pragma unroll
    for (int k = 0; k < 16; ++k) {
        int r = k * 4 + r0;
        tl[r][c] = f32_bf16(in[(size_t)(tr * 64 + r) * C + tc * 64 + c]);
    }
    __syncthreads();
#pragma unroll
    for (int k = 0; k < 16; ++k) {
        int r2 = k * 4 + r0;
        out[(size_t)(tc * 64 + r2) * R + tr * 64 + c] = tl[c][r2];
    }
}

// ---------------- transpose V: vb [b,s,h,d] -> vtb [b*12+h][64][2048] ----------------
__global__ __launch_bounds__(256) void k_transpose_v(const unsigned short* __restrict__ vb,
                                                     unsigned short* __restrict__ vtb) {
    __shared__ unsigned short tl[64][68];
    const int bh = blockIdx.y;
    const int s0 = blockIdx.x * 64;
    const unsigned short* in = vb + ((size_t)((bh / 12) * 2048 + s0)) * 768 + (bh % 12) * 64;
    unsigned short* outp = vtb + (size_t)bh * 64 * 2048 + s0;
    const int t = threadIdx.x, c = t & 63, r0 = t >> 6;
#pragma unroll
    for (int k = 0; k < 16; ++k) {
        int r = k * 4 + r0;
        tl[r][c] = in[(size_t)r * 768 + c];
    }
    __syncthreads();
#pragma unroll
    for (int k = 0; k < 16; ++k) {
        int r2 = k * 4 + r0;
        outp[(size_t)r2 * 2048 + c] = tl[c][r2];
    }
}

// ---------------- GEMM: C[4096][768] = A[4096][768] @ B (BT = B^T [768][768]) + bias ---
// BM=128 BN=64 BK=32, 256 thr = 4 waves in 2x2, wave tile 64x32, mfma 16x16x32 bf16.
template <bool BOUT>
__global__ __launch_bounds__(256) void k_gemm(const unsigned short* __restrict__ A,
                                              const unsigned short* __restrict__ BT,
                                              const float* __restrict__ bias,
                                              unsigned short* __restrict__ outb,
                                              float* __restrict__ outf) {
    __shared__ alignas(16) unsigned short As[128][40];
    __shared__ alignas(16) unsigned short Bs[64][40];
    const int t = threadIdx.x;
    const int w = t >> 6, l = t & 63, lr = l & 15, lg = l >> 4;
    const int wr = (w >> 1) * 64, wc = (w & 1) * 32;
    const int m0 = blockIdx.y * 128;
    const int n0 = blockIdx.x * 64;

    f32x4 acc[4][2] = {};

    for (int kt = 0; kt < 24; ++kt) {
        const int k0 = kt * 32;
        __syncthreads();
        {
            const int s1 = t, s2 = t + 256;
            *(uint4*)&As[s1 >> 2][(s1 & 3) * 8] =
                *(const uint4*)(A + (size_t)(m0 + (s1 >> 2)) * 768 + k0 + (s1 & 3) * 8);
            *(uint4*)&As[s2 >> 2][(s2 & 3) * 8] =
                *(const uint4*)(A + (size_t)(m0 + (s2 >> 2)) * 768 + k0 + (s2 & 3) * 8);
            *(uint4*)&Bs[t >> 2][(t & 3) * 8] =
                *(const uint4*)(BT + (size_t)(n0 + (t >> 2)) * 768 + k0 + (t & 3) * 8);
        }
        __syncthreads();

        bf16x8 af[4], bfr[2];
#pragma unroll
        for (int ri = 0; ri < 4; ++ri)
            af[ri] = *(const bf16x8*)&As[wr + ri * 16 + lr][lg * 8];
#pragma unroll
        for (int cj = 0; cj < 2; ++cj)
            bfr[cj] = *(const bf16x8*)&Bs[wc + cj * 16 + lr][lg * 8];
#pragma unroll
        for (int ri = 0; ri < 4; ++ri)
#pragma unroll
            for (int cj = 0; cj < 2; ++cj)
                acc[ri][cj] = __builtin_amdgcn_mfma_f32_16x16x32_bf16(
                    af[ri], bfr[cj], acc[ri][cj], 0, 0, 0);
    }

#pragma unroll
    for (int cj = 0; cj < 2; ++cj) {
        const int col = n0 + wc + cj * 16 + lr;
        const float bv = bias[col];
#pragma unroll
        for (int ri = 0; ri < 4; ++ri)
#pragma unroll
            for (int e = 0; e < 4; ++e) {
                const int row = m0 + wr + ri * 16 + lg * 4 + e;
                const float v = acc[ri][cj][e] + bv;
                if (BOUT) outb[(size_t)row * 768 + col] = f32_bf16(v);
                else      outf[(size_t)row * 768 + col] = v;
            }
    }
}

// ---------------- flash attention ----------------
// block = (qi, h, b); QBLK=128 (4 waves x 32 rows), KVBLK=64.
__global__ __launch_bounds__(256) void k_flash(const unsigned short* __restrict__ qb,
                                               const unsigned short* __restrict__ kb,
                                               const unsigned short* __restrict__ vtb,
                                               unsigned short* __restrict__ zb) {
    __shared__ alignas(16) unsigned short k_lds[64][72];
    __shared__ alignas(16) unsigned short v_lds[64][72];
    __shared__ alignas(16) unsigned short p_lds[4][32][72];

    const int qi = blockIdx.x, h = blockIdx.y, b = blockIdx.z;
    const int q0 = qi * 128;
    const int t = threadIdx.x, w = t >> 6, l = t & 63, lr = l & 15, lg = l >> 4;
    const int qrow = q0 + w * 32;
    const float SL2 = 0.18033688011112042f;  // 0.125 * log2(e)

    bf16x8 qf[2][2];
#pragma unroll
    for (int ri = 0; ri < 2; ++ri)
#pragma unroll
        for (int kk = 0; kk < 2; ++kk)
            qf[ri][kk] = *(const bf16x8*)(qb + (size_t)(b * 2048 + qrow + ri * 16 + lr) * 768 +
                                          h * 64 + kk * 32 + lg * 8);

    f32x4 o[2][4] = {};
    f32x4 m2[2], ls[2];
#pragma unroll
    for (int ri = 0; ri < 2; ++ri)
#pragma unroll
        for (int e = 0; e < 4; ++e) { m2[ri][e] = -INFINITY; ls[ri][e] = 0.f; }

    const size_t kbase = (size_t)(b * 2048) * 768 + h * 64;
    const size_t vbase = (size_t)(b * 12 + h) * 64 * 2048;
    const int nkv = (q0 + 128) >> 6;

    for (int kt = 0; kt < nkv; ++kt) {
        const int kv0 = kt * 64;
        __syncthreads();
        {
            const int s1 = t, s2 = t + 256;
            *(uint4*)&k_lds[s1 >> 3][(s1 & 7) * 8] =
                *(const uint4*)(kb + kbase + (size_t)(kv0 + (s1 >> 3)) * 768 + (s1 & 7) * 8);
            *(uint4*)&k_lds[s2 >> 3][(s2 & 7) * 8] =
                *(const uint4*)(kb + kbase + (size_t)(kv0 + (s2 >> 3)) * 768 + (s2 & 7) * 8);
            *(uint4*)&v_lds[s1 >> 3][(s1 & 7) * 8] =
                *(const uint4*)(vtb + vbase + (size_t)(s1 >> 3) * 2048 + kv0 + (s1 & 7) * 8);
            *(uint4*)&v_lds[s2 >> 3][(s2 & 7) * 8] =
                *(const uint4*)(vtb + vbase + (size_t)(s2 >> 3) * 2048 + kv0 + (s2 & 7) * 8);
        }
        __syncthreads();

        bf16x8 kf[4][2];
#pragma unroll
        for (int cj = 0; cj < 4; ++cj)
#pragma unroll
            for (int kk = 0; kk < 2; ++kk)
                kf[cj][kk] = *(const bf16x8*)&k_lds[cj * 16 + lr][kk * 32 + lg * 8];

        f32x4 sc[2][4];
        const f32x4 zz = {0.f, 0.f, 0.f, 0.f};
#pragma unroll
        for (int ri = 0; ri < 2; ++ri)
#pragma unroll
            for (int cj = 0; cj < 4; ++cj) {
                f32x4 a0 = __builtin_amdgcn_mfma_f32_16x16x32_bf16(qf[ri][0], kf[cj][0], zz, 0, 0, 0);
                sc[ri][cj] = __builtin_amdgcn_mfma_f32_16x16x32_bf16(qf[ri][1], kf[cj][1], a0, 0, 0, 0);
            }

        if (kv0 + 63 > qrow) {  // wave-uniform: diagonal tile needs masking
#pragma unroll
            for (int ri = 0; ri < 2; ++ri)
#pragma unroll
                for (int cj = 0; cj < 4; ++cj)
#pragma unroll
                    for (int e = 0; e < 4; ++e) {
                        const int row = qrow + ri * 16 + lg * 4 + e;
                        const int col = kv0 + cj * 16 + lr;
                        if (col > row) sc[ri][cj][e] = -1e30f;
                    }
        }

#pragma unroll
        for (int ri = 0; ri < 2; ++ri) {
            f32x4 mx = sc[ri][0];
#pragma unroll
            for (int cj = 1; cj < 4; ++cj)
#pragma unroll
                for (int e = 0; e < 4; ++e) mx[e] = fmaxf(mx[e], sc[ri][cj][e]);
#pragma unroll
            for (int msk = 1; msk < 16; msk <<= 1)
#pragma unroll
                for (int e = 0; e < 4; ++e) mx[e] = fmaxf(mx[e], __shfl_xor(mx[e], msk, 64));

            f32x4 m2n, fs;
#pragma unroll
            for (int e = 0; e < 4; ++e) m2n[e] = fmaxf(m2[ri][e], mx[e] * SL2);
#pragma unroll
            for (int e = 0; e < 4; ++e) fs[e] = __builtin_amdgcn_exp2f(m2[ri][e] - m2n[e]);
            m2[ri] = m2n;
#pragma unroll
            for (int e = 0; e < 4; ++e) ls[ri][e] *= fs[e];
#pragma unroll
            for (int dj = 0; dj < 4; ++dj)
#pragma unroll
                for (int e = 0; e < 4; ++e) o[ri][dj][e] *= fs[e];

            f32x4 ps = {0.f, 0.f, 0.f, 0.f};
#pragma unroll
            for (int cj = 0; cj < 4; ++cj)
#pragma unroll
                for (int e = 0; e < 4; ++e) {
                    const float p = __builtin_amdgcn_exp2f(sc[ri][cj][e] * SL2 - m2n[e]);
                    sc[ri][cj][e] = p;
                    ps[e] += p;
                }
#pragma unroll
            for (int msk = 1; msk < 16; msk <<= 1)
#pragma unroll
                for (int e = 0; e < 4; ++e) ps[e] += __shfl_xor(ps[e], msk, 64);
#pragma unroll
            for (int e = 0; e < 4; ++e) ls[ri][e] += ps[e];

#pragma unroll
            for (int cj = 0; cj < 4; ++cj)
#pragma unroll
                for (int e = 0; e < 4; ++e)
                    p_lds[w][ri * 16 + lg * 4 + e][cj * 16 + lr] = f32_bf16(sc[ri][cj][e]);
        }

        bf16x8 vf[2][4];
#pragma unroll
        for (int kk = 0; kk < 2; ++kk)
#pragma unroll
            for (int dj = 0; dj < 4; ++dj)
                vf[kk][dj] = *(const bf16x8*)&v_lds[dj * 16 + lr][kk * 32 + lg * 8];
#pragma unroll
        for (int ri = 0; ri < 2; ++ri) {
            bf16x8 pa0 = *(const bf16x8*)&p_lds[w][ri * 16 + lr][lg * 8];
            bf16x8 pa1 = *(const bf16x8*)&p_lds[w][ri * 16 + lr][32 + lg * 8];
#pragma unroll
            for (int dj = 0; dj < 4; ++dj) {
                f32x4 tmp = __builtin_amdgcn_mfma_f32_16x16x32_bf16(pa0, vf[0][dj], o[ri][dj], 0, 0, 0);
                o[ri][dj] = __builtin_amdgcn_mfma_f32_16x16x32_bf16(pa1, vf[1][dj], tmp, 0, 0, 0);
            }
        }
    }

#pragma unroll
    for (int ri = 0; ri < 2; ++ri)
#pragma unroll
        for (int dj = 0; dj < 4; ++dj)
#pragma unroll
            for (int e = 0; e < 4; ++e) {
                const int srow = qrow + ri * 16 + lg * 4 + e;
                const float v = o[ri][dj][e] / ls[ri][e];
                zb[(size_t)(b * 2048 + srow) * 768 + h * 64 + dj * 16 + lr] = f32_bf16(v);
            }
}

extern "C" void kernel_launch(void* const* d_in, const int* in_sizes, int n_in,
                              void* d_out, int out_size, void* d_ws, size_t ws_size,
                              hipStream_t stream) {
    (void)in_sizes; (void)n_in; (void)out_size; (void)ws_size;
    const float* x   = (const float*)d_in[0];
    const float* W_Q = (const float*)d_in[1];
    const float* W_K = (const float*)d_in[2];
    const float* W_V = (const float*)d_in[3];
    const float* b_Q = (const float*)d_in[4];
    const float* b_K = (const float*)d_in[5];
    const float* b_V = (const float*)d_in[6];
    const float* W_O = (const float*)d_in[7];
    const float* b_O = (const float*)d_in[8];
    float* out = (float*)d_out;

    char* ws = (char*)d_ws;
    unsigned short* xb  = (unsigned short*)(ws);
    unsigned short* qb  = (unsigned short*)(ws + 6291456);
    unsigned short* kb  = (unsigned short*)(ws + 12582912);
    unsigned short* vb  = (unsigned short*)(ws + 18874368);
    unsigned short* vtb = (unsigned short*)(ws + 25165824);
    unsigned short* wqT = (unsigned short*)(ws + 31457280);
    unsigned short* wkT = (unsigned short*)(ws + 32636928);
    unsigned short* wvT = (unsigned short*)(ws + 33816576);
    unsigned short* woT = (unsigned short*)(ws + 34996224);
    unsigned short* zb  = xb;  // xb dead after the 3 QKV GEMMs

    k_convert<<<3072, 256, 0, stream>>>(x, xb);
    k_transpose_w<<<dim3(12, 12), 256, 0, stream>>>(W_Q, wqT, 768, 64, 12);
    k_transpose_w<<<dim3(12, 12), 256, 0, stream>>>(W_K, wkT, 768, 64, 12);
    k_transpose_w<<<dim3(12, 12), 256, 0, stream>>>(W_V, wvT, 768, 64, 12);
    k_transpose_w<<<dim3(144, 1), 256, 0, stream>>>(W_O, woT, 768, 768, 12);

    k_gemm<true><<<dim3(12, 32), 256, 0, stream>>>(xb, wqT, b_Q, qb, nullptr);
    k_gemm<true><<<dim3(12, 32), 256, 0, stream>>>(xb, wkT, b_K, kb, nullptr);
    k_gemm<true><<<dim3(12, 32), 256, 0, stream>>>(xb, wvT, b_V, vb, nullptr);

    k_transpose_v<<<dim3(32, 24), 256, 0, stream>>>(vb, vtb);
    k_flash<<<dim3(16, 12, 2), 256, 0, stream>>>(qb, kb, vtb, zb);
    k_gemm<false><<<dim3(12, 32), 256, 0, stream>>>(zb, woT, b_O, nullptr, out);
}

// Round 2
// 168.634 us; speedup vs baseline: 1.2632x; 1.2632x over previous
//
#include <hip/hip_runtime.h>

// Fused causal MHA on gfx950.  Pipeline (R1):
//   k_convert:        x fp32 -> xb bf16                         [4096][768]
//   k_transpose_wqkv: W_Q|W_K|W_V fp32 [h][768][64] -> wqkvT bf16 [2304][768]
//   k_transpose_w:    W_O fp32 [768][768] -> woT bf16 [768][768]^T
//   k_gemm<128,true>: qkvb bf16 [4096][2304] = xb @ wqkvT^T + bias  (Q cols pre-scaled by 0.125*log2e)
//   k_transpose_v:    qkvb(v cols) -> vtb [24][64][2048]
//   k_flash:          QBLK=64 (4 waves x 16 rows), KVBLK=64, reversed-qi, skip-rescale
//   k_gemm<64,false>: d_out fp32 = zb @ woT^T + b_O
//
// ws: xb/zb @0 (6291456) | qkvb @6291456 (18874368) | vtb @25165824 (6291456)
//     wqkvT @31457280 (3538944) | woT @34996224 (1179648)   total 36175872 B

#define DEVINL __device__ __forceinline__

using bf16x8 = __attribute__((ext_vector_type(8))) __bf16;
using f32x4  = __attribute__((ext_vector_type(4))) float;

DEVINL unsigned short f32_bf16(float f) {
    unsigned u = __builtin_bit_cast(unsigned, f);
    return (unsigned short)((u + 0x7FFFu + ((u >> 16) & 1u)) >> 16);
}

// ---------------- convert fp32 -> bf16, 4 elems/thread ----------------
__global__ __launch_bounds__(256) void k_convert(const float* __restrict__ in,
                                                 unsigned short* __restrict__ out) {
    int i = (blockIdx.x * 256 + threadIdx.x) * 4;
    float4 v = *(const float4*)(in + i);
    ushort4 o;
    o.x = f32_bf16(v.x); o.y = f32_bf16(v.y); o.z = f32_bf16(v.z); o.w = f32_bf16(v.w);
    *(ushort4*)(out + i) = o;
}

// ---------------- transpose + convert: in fp32 [R][C] -> out bf16 [C][R], batched ----
__global__ __launch_bounds__(256) void k_transpose_w(const float* __restrict__ in,
                                                     unsigned short* __restrict__ out,
                                                     int R, int C, int tilesR) {
    __shared__ unsigned short tl[64][68];
    const int batch = blockIdx.y;
    const int tr = blockIdx.x % tilesR, tc = blockIdx.x / tilesR;
    in  += (size_t)batch * R * C;
    out += (size_t)batch * R * C;
    const int t = threadIdx.x, c = t & 63, r0 = t >> 6;
#pragma unroll
    for (int k = 0; k < 16; ++k) {
        int r = k * 4 + r0;
        tl[r][c] = f32_bf16(in[(size_t)(tr * 64 + r) * C + tc * 64 + c]);
    }
    __syncthreads();
#pragma unroll
    for (int k = 0; k < 16; ++k) {
        int r2 = k * 4 + r0;
        out[(size_t)(tc * 64 + r2) * R + tr * 64 + c] = tl[c][r2];
    }
}

// ---------------- fused W_Q/W_K/W_V transpose -> wqkvT [2304][768] ----------------
__global__ __launch_bounds__(256) void k_transpose_wqkv(const float* __restrict__ Wq,
                                                        const float* __restrict__ Wk,
                                                        const float* __restrict__ Wv,
                                                        unsigned short* __restrict__ out) {
    __shared__ unsigned short tl[64][68];
    const int batch = blockIdx.y;               // 0..35
    const int tr = blockIdx.x;                  // 0..11 (768/64)
    const float* src = (batch < 12) ? Wq : (batch < 24) ? Wk : Wv;
    src += (size_t)(batch % 12) * 768 * 64;
    out += (size_t)batch * 64 * 768;
    const int t = threadIdx.x, c = t & 63, r0 = t >> 6;
#pragma unroll
    for (int k = 0; k < 16; ++k) {
        int r = k * 4 + r0;
        tl[r][c] = f32_bf16(src[(size_t)(tr * 64 + r) * 64 + c]);
    }
    __syncthreads();
#pragma unroll
    for (int k = 0; k < 16; ++k) {
        int r2 = k * 4 + r0;
        out[(size_t)r2 * 768 + tr * 64 + c] = tl[c][r2];
    }
}

// ---------------- transpose V: qkvb v-cols [b,s,2304] -> vtb [b*12+h][64][2048] -------
__global__ __launch_bounds__(256) void k_transpose_v(const unsigned short* __restrict__ vb,
                                                     unsigned short* __restrict__ vtb) {
    __shared__ unsigned short tl[64][68];
    const int bh = blockIdx.y;
    const int s0 = blockIdx.x * 64;
    const unsigned short* in = vb + ((size_t)((bh / 12) * 2048 + s0)) * 2304 + (bh % 12) * 64;
    unsigned short* outp = vtb + (size_t)bh * 64 * 2048 + s0;
    const int t = threadIdx.x, c = t & 63, r0 = t >> 6;
#pragma unroll
    for (int k = 0; k < 16; ++k) {
        int r = k * 4 + r0;
        tl[r][c] = in[(size_t)r * 2304 + c];
    }
    __syncthreads();
#pragma unroll
    for (int k = 0; k < 16; ++k) {
        int r2 = k * 4 + r0;
        outp[(size_t)r2 * 2048 + c] = tl[c][r2];
    }
}

// ---------------- GEMM: C[4096][N] = A[4096][768] @ BT[N][768] + bias ----------------
// BN=64, BK=32, 256 thr = 4 waves 2x2, mfma 16x16x32 bf16.
// QKV=true: N=2304, out bf16 stride 2304, bias segment-select, Q cols scaled by SL2.
// QKV=false: N=768, out fp32 stride 768, bias b0.
template <int BM, bool QKV>
__global__ __launch_bounds__(256) void k_gemm(const unsigned short* __restrict__ A,
                                              const unsigned short* __restrict__ BT,
                                              const float* __restrict__ b0,
                                              const float* __restrict__ b1,
                                              const float* __restrict__ b2,
                                              unsigned short* __restrict__ outb,
                                              float* __restrict__ outf) {
    constexpr int WM = BM / 2;       // wave tile rows
    constexpr int WR = WM / 16;      // acc row frags
    constexpr int LDC = QKV ? 2304 : 768;
    __shared__ alignas(16) unsigned short As[BM][40];
    __shared__ alignas(16) unsigned short Bs[64][40];
    const int t = threadIdx.x;
    const int w = t >> 6, l = t & 63, lr = l & 15, lg = l >> 4;
    const int wr = (w >> 1) * WM, wc = (w & 1) * 32;
    const int m0 = blockIdx.y * BM;
    const int n0 = blockIdx.x * 64;

    f32x4 acc[WR][2] = {};

    for (int kt = 0; kt < 24; ++kt) {
        const int k0 = kt * 32;
        __syncthreads();
#pragma unroll
        for (int i = 0; i < BM / 64; ++i) {
            const int s = t + i * 256;
            *(uint4*)&As[s >> 2][(s & 3) * 8] =
                *(const uint4*)(A + (size_t)(m0 + (s >> 2)) * 768 + k0 + (s & 3) * 8);
        }
        *(uint4*)&Bs[t >> 2][(t & 3) * 8] =
            *(const uint4*)(BT + (size_t)(n0 + (t >> 2)) * 768 + k0 + (t & 3) * 8);
        __syncthreads();

        bf16x8 af[WR], bfr[2];
#pragma unroll
        for (int ri = 0; ri < WR; ++ri)
            af[ri] = *(const bf16x8*)&As[wr + ri * 16 + lr][lg * 8];
#pragma unroll
        for (int cj = 0; cj < 2; ++cj)
            bfr[cj] = *(const bf16x8*)&Bs[wc + cj * 16 + lr][lg * 8];
        __builtin_amdgcn_s_setprio(1);
#pragma unroll
        for (int ri = 0; ri < WR; ++ri)
#pragma unroll
            for (int cj = 0; cj < 2; ++cj)
                acc[ri][cj] = __builtin_amdgcn_mfma_f32_16x16x32_bf16(
                    af[ri], bfr[cj], acc[ri][cj], 0, 0, 0);
        __builtin_amdgcn_s_setprio(0);
    }

#pragma unroll
    for (int cj = 0; cj < 2; ++cj) {
        const int col = n0 + wc + cj * 16 + lr;
        const float* bp = b0;
        int cc = col;
        if (QKV) {
            if (col >= 1536)      { bp = b2; cc = col - 1536; }
            else if (col >= 768)  { bp = b1; cc = col - 768; }
        }
        const float bv = bp[cc];
        const float scl = (QKV && col < 768) ? 0.18033688011112042f : 1.0f;  // 0.125*log2e
#pragma unroll
        for (int ri = 0; ri < WR; ++ri)
#pragma unroll
            for (int e = 0; e < 4; ++e) {
                const int row = m0 + wr + ri * 16 + lg * 4 + e;
                const float v = (acc[ri][cj][e] + bv) * scl;
                if (QKV) outb[(size_t)row * LDC + col] = f32_bf16(v);
                else     outf[(size_t)row * LDC + col] = v;
            }
    }
}

// ---------------- flash attention ----------------
// block = (qi rev, h, b); QBLK=64 (4 waves x 16 rows), KVBLK=64. Scores pre-scaled
// into exp2 domain by the Q-GEMM epilogue.
__global__ __launch_bounds__(256) void k_flash(const unsigned short* __restrict__ qb,
                                               const unsigned short* __restrict__ kb,
                                               const unsigned short* __restrict__ vtb,
                                               unsigned short* __restrict__ zb) {
    __shared__ alignas(16) unsigned short k_lds[64][72];
    __shared__ alignas(16) unsigned short v_lds[64][72];
    __shared__ alignas(16) unsigned short p_lds[4][16][72];

    const int qi = (int)gridDim.x - 1 - (int)blockIdx.x;  // longest blocks first
    const int h = blockIdx.y, b = blockIdx.z;
    const int q0 = qi * 64;
    const int t = threadIdx.x, w = t >> 6, l = t & 63, lr = l & 15, lg = l >> 4;
    const int qrow = q0 + w * 16;

    bf16x8 qf[2];
#pragma unroll
    for (int kk = 0; kk < 2; ++kk)
        qf[kk] = *(const bf16x8*)(qb + (size_t)(b * 2048 + qrow + lr) * 2304 +
                                  h * 64 + kk * 32 + lg * 8);

    f32x4 o[4] = {};
    f32x4 m2, ls;
#pragma unroll
    for (int e = 0; e < 4; ++e) { m2[e] = -INFINITY; ls[e] = 0.f; }

    const size_t kbase = (size_t)(b * 2048) * 2304 + h * 64;
    const size_t vbase = (size_t)(b * 12 + h) * 64 * 2048;
    const int nkv = qi + 1;

    for (int kt = 0; kt < nkv; ++kt) {
        const int kv0 = kt * 64;
        __syncthreads();
        {
            const int s1 = t, s2 = t + 256;
            *(uint4*)&k_lds[s1 >> 3][(s1 & 7) * 8] =
                *(const uint4*)(kb + kbase + (size_t)(kv0 + (s1 >> 3)) * 2304 + (s1 & 7) * 8);
            *(uint4*)&k_lds[s2 >> 3][(s2 & 7) * 8] =
                *(const uint4*)(kb + kbase + (size_t)(kv0 + (s2 >> 3)) * 2304 + (s2 & 7) * 8);
            *(uint4*)&v_lds[s1 >> 3][(s1 & 7) * 8] =
                *(const uint4*)(vtb + vbase + (size_t)(s1 >> 3) * 2048 + kv0 + (s1 & 7) * 8);
            *(uint4*)&v_lds[s2 >> 3][(s2 & 7) * 8] =
                *(const uint4*)(vtb + vbase + (size_t)(s2 >> 3) * 2048 + kv0 + (s2 & 7) * 8);
        }
        __syncthreads();

        bf16x8 kf[4][2];
#pragma unroll
        for (int cj = 0; cj < 4; ++cj)
#pragma unroll
            for (int kk = 0; kk < 2; ++kk)
                kf[cj][kk] = *(const bf16x8*)&k_lds[cj * 16 + lr][kk * 32 + lg * 8];

        f32x4 sc[4];
        const f32x4 zz = {0.f, 0.f, 0.f, 0.f};
        __builtin_amdgcn_s_setprio(1);
#pragma unroll
        for (int cj = 0; cj < 4; ++cj) {
            f32x4 a0 = __builtin_amdgcn_mfma_f32_16x16x32_bf16(qf[0], kf[cj][0], zz, 0, 0, 0);
            sc[cj] = __builtin_amdgcn_mfma_f32_16x16x32_bf16(qf[1], kf[cj][1], a0, 0, 0, 0);
        }
        __builtin_amdgcn_s_setprio(0);

        if (kv0 + 63 > qrow) {  // wave-uniform: diagonal tile needs masking
#pragma unroll
            for (int cj = 0; cj < 4; ++cj)
#pragma unroll
                for (int e = 0; e < 4; ++e) {
                    const int row = qrow + lg * 4 + e;
                    const int col = kv0 + cj * 16 + lr;
                    if (col > row) sc[cj][e] = -1e30f;
                }
        }

        // --- online softmax (scores already in exp2 domain) ---
        f32x4 mx = sc[0];
#pragma unroll
        for (int cj = 1; cj < 4; ++cj)
#pragma unroll
            for (int e = 0; e < 4; ++e) mx[e] = fmaxf(mx[e], sc[cj][e]);
#pragma unroll
        for (int msk = 1; msk < 16; msk <<= 1)
#pragma unroll
            for (int e = 0; e < 4; ++e) mx[e] = fmaxf(mx[e], __shfl_xor(mx[e], msk, 64));

        f32x4 m2n;
        bool grow = false;
#pragma unroll
        for (int e = 0; e < 4; ++e) {
            m2n[e] = fmaxf(m2[e], mx[e]);
            grow |= (m2n[e] > m2[e]);
        }
        if (__any(grow)) {  // exact skip: if max unchanged, rescale factor is exactly 1
#pragma unroll
            for (int e = 0; e < 4; ++e) {
                const float fs = __builtin_amdgcn_exp2f(m2[e] - m2n[e]);
                ls[e] *= fs;
#pragma unroll
                for (int dj = 0; dj < 4; ++dj) o[dj][e] *= fs;
                m2[e] = m2n[e];
            }
        }

        f32x4 ps = {0.f, 0.f, 0.f, 0.f};
#pragma unroll
        for (int cj = 0; cj < 4; ++cj)
#pragma unroll
            for (int e = 0; e < 4; ++e) {
                const float p = __builtin_amdgcn_exp2f(sc[cj][e] - m2[e]);
                sc[cj][e] = p;
                ps[e] += p;
            }
#pragma unroll
        for (int msk = 1; msk < 16; msk <<= 1)
#pragma unroll
            for (int e = 0; e < 4; ++e) ps[e] += __shfl_xor(ps[e], msk, 64);
#pragma unroll
        for (int e = 0; e < 4; ++e) ls[e] += ps[e];

#pragma unroll
        for (int cj = 0; cj < 4; ++cj)
#pragma unroll
            for (int e = 0; e < 4; ++e)
                p_lds[w][lg * 4 + e][cj * 16 + lr] = f32_bf16(sc[cj][e]);

        bf16x8 vf[2][4];
#pragma unroll
        for (int kk = 0; kk < 2; ++kk)
#pragma unroll
            for (int dj = 0; dj < 4; ++dj)
                vf[kk][dj] = *(const bf16x8*)&v_lds[dj * 16 + lr][kk * 32 + lg * 8];

        bf16x8 pa0 = *(const bf16x8*)&p_lds[w][lr][lg * 8];
        bf16x8 pa1 = *(const bf16x8*)&p_lds[w][lr][32 + lg * 8];
        __builtin_amdgcn_s_setprio(1);
#pragma unroll
        for (int dj = 0; dj < 4; ++dj) {
            f32x4 tmp = __builtin_amdgcn_mfma_f32_16x16x32_bf16(pa0, vf[0][dj], o[dj], 0, 0, 0);
            o[dj] = __builtin_amdgcn_mfma_f32_16x16x32_bf16(pa1, vf[1][dj], tmp, 0, 0, 0);
        }
        __builtin_amdgcn_s_setprio(0);
    }

#pragma unroll
    for (int dj = 0; dj < 4; ++dj)
#pragma unroll
        for (int e = 0; e < 4; ++e) {
            const int srow = qrow + lg * 4 + e;
            const float v = o[dj][e] / ls[e];
            zb[(size_t)(b * 2048 + srow) * 768 + h * 64 + dj * 16 + lr] = f32_bf16(v);
        }
}

extern "C" void kernel_launch(void* const* d_in, const int* in_sizes, int n_in,
                              void* d_out, int out_size, void* d_ws, size_t ws_size,
                              hipStream_t stream) {
    (void)in_sizes; (void)n_in; (void)out_size; (void)ws_size;
    const float* x   = (const float*)d_in[0];
    const float* W_Q = (const float*)d_in[1];
    const float* W_K = (const float*)d_in[2];
    const float* W_V = (const float*)d_in[3];
    const float* b_Q = (const float*)d_in[4];
    const float* b_K = (const float*)d_in[5];
    const float* b_V = (const float*)d_in[6];
    const float* W_O = (const float*)d_in[7];
    const float* b_O = (const float*)d_in[8];
    float* out = (float*)d_out;

    char* ws = (char*)d_ws;
    unsigned short* xb    = (unsigned short*)(ws);
    unsigned short* qkvb  = (unsigned short*)(ws + 6291456);
    unsigned short* vtb   = (unsigned short*)(ws + 25165824);
    unsigned short* wqkvT = (unsigned short*)(ws + 31457280);
    unsigned short* woT   = (unsigned short*)(ws + 34996224);
    unsigned short* zb    = xb;  // xb dead after the QKV GEMM

    k_convert<<<3072, 256, 0, stream>>>(x, xb);
    k_transpose_wqkv<<<dim3(12, 36), 256, 0, stream>>>(W_Q, W_K, W_V, wqkvT);
    k_transpose_w<<<dim3(144, 1), 256, 0, stream>>>(W_O, woT, 768, 768, 12);

    k_gemm<128, true><<<dim3(36, 32), 256, 0, stream>>>(xb, wqkvT, b_Q, b_K, b_V, qkvb, nullptr);

    k_transpose_v<<<dim3(32, 24), 256, 0, stream>>>(qkvb + 1536, vtb);
    k_flash<<<dim3(32, 12, 2), 256, 0, stream>>>(qkvb, qkvb + 768, vtb, zb);
    k_gemm<64, false><<<dim3(12, 64), 256, 0, stream>>>(zb, woT, b_O, b_O, b_O, nullptr, out);
}

// Round 5
// 135.276 us; speedup vs baseline: 1.5747x; 1.2466x over previous
//
#include <hip/hip_runtime.h>

// Fused causal MHA on gfx950.  Pipeline (R4 = R2 structure + merge-buffer size fix):
//   k_convert:        x fp32 -> xb bf16                         [4096][768]
//   k_transpose_wqkv: W_Q|W_K|W_V fp32 [h][768][64] -> wqkvT bf16 [2304][768]
//   k_transpose_w:    W_O fp32 [768][768] -> woT bf16 [768][768]^T
//   k_gemm<128,true>: qkvb bf16 [4096][2304] = xb @ wqkvT^T + bias  (Q pre-scaled by 0.125*log2e)
//   k_transpose_v:    qkvb(v cols) -> vtb [24][64][2048]
//   k_flash:          QBLK=32, 4 waves SPLIT the KV range (wave w: tiles w,w+4,..),
//                     private (m,l,o) partials, in-block LDS merge. No in-loop barriers.
//                     R2/R3 bug: merge region was [32][33] f32 but O is [32][64] ->
//                     LDS overflow. Now per-wave region = 8704 B ([32][68] f32).
//   k_gemm<64,false>: d_out fp32 = zb @ woT^T + b_O
//
// ws: xb/zb @0 (6291456) | qkvb @6291456 (18874368) | vtb @25165824 (6291456)
//     wqkvT @31457280 (3538944) | woT @34996224 (1179648)   total 36175872 B

#define DEVINL __device__ __forceinline__

using bf16x8 = __attribute__((ext_vector_type(8))) __bf16;
using f32x4  = __attribute__((ext_vector_type(4))) float;

DEVINL unsigned short f32_bf16(float f) {
    unsigned u = __builtin_bit_cast(unsigned, f);
    return (unsigned short)((u + 0x7FFFu + ((u >> 16) & 1u)) >> 16);
}
DEVINL __bf16 f32_bf16h(float f) { return __builtin_bit_cast(__bf16, f32_bf16(f)); }

// ---------------- convert fp32 -> bf16, 4 elems/thread ----------------
__global__ __launch_bounds__(256) void k_convert(const float* __restrict__ in,
                                                 unsigned short* __restrict__ out) {
    int i = (blockIdx.x * 256 + threadIdx.x) * 4;
    float4 v = *(const float4*)(in + i);
    ushort4 o;
    o.x = f32_bf16(v.x); o.y = f32_bf16(v.y); o.z = f32_bf16(v.z); o.w = f32_bf16(v.w);
    *(ushort4*)(out + i) = o;
}

// ---------------- transpose + convert: in fp32 [R][C] -> out bf16 [C][R], batched ----
__global__ __launch_bounds__(256) void k_transpose_w(const float* __restrict__ in,
                                                     unsigned short* __restrict__ out,
                                                     int R, int C, int tilesR) {
    __shared__ unsigned short tl[64][68];
    const int batch = blockIdx.y;
    const int tr = blockIdx.x % tilesR, tc = blockIdx.x / tilesR;
    in  += (size_t)batch * R * C;
    out += (size_t)batch * R * C;
    const int t = threadIdx.x, c = t & 63, r0 = t >> 6;
#pragma unroll
    for (int k = 0; k < 16; ++k) {
        int r = k * 4 + r0;
        tl[r][c] = f32_bf16(in[(size_t)(tr * 64 + r) * C + tc * 64 + c]);
    }
    __syncthreads();
#pragma unroll
    for (int k = 0; k < 16; ++k) {
        int r2 = k * 4 + r0;
        out[(size_t)(tc * 64 + r2) * R + tr * 64 + c] = tl[c][r2];
    }
}

// ---------------- fused W_Q/W_K/W_V transpose -> wqkvT [2304][768] ----------------
__global__ __launch_bounds__(256) void k_transpose_wqkv(const float* __restrict__ Wq,
                                                        const float* __restrict__ Wk,
                                                        const float* __restrict__ Wv,
                                                        unsigned short* __restrict__ out) {
    __shared__ unsigned short tl[64][68];
    const int batch = blockIdx.y;               // 0..35
    const int tr = blockIdx.x;                  // 0..11 (768/64)
    const float* src = (batch < 12) ? Wq : (batch < 24) ? Wk : Wv;
    src += (size_t)(batch % 12) * 768 * 64;
    out += (size_t)batch * 64 * 768;
    const int t = threadIdx.x, c = t & 63, r0 = t >> 6;
#pragma unroll
    for (int k = 0; k < 16; ++k) {
        int r = k * 4 + r0;
        tl[r][c] = f32_bf16(src[(size_t)(tr * 64 + r) * 64 + c]);
    }
    __syncthreads();
#pragma unroll
    for (int k = 0; k < 16; ++k) {
        int r2 = k * 4 + r0;
        out[(size_t)r2 * 768 + tr * 64 + c] = tl[c][r2];
    }
}

// ---------------- transpose V: qkvb v-cols [b,s,2304] -> vtb [b*12+h][64][2048] -------
__global__ __launch_bounds__(256) void k_transpose_v(const unsigned short* __restrict__ vb,
                                                     unsigned short* __restrict__ vtb) {
    __shared__ unsigned short tl[64][68];
    const int bh = blockIdx.y;
    const int s0 = blockIdx.x * 64;
    const unsigned short* in = vb + ((size_t)((bh / 12) * 2048 + s0)) * 2304 + (bh % 12) * 64;
    unsigned short* outp = vtb + (size_t)bh * 64 * 2048 + s0;
    const int t = threadIdx.x, c = t & 63, r0 = t >> 6;
#pragma unroll
    for (int k = 0; k < 16; ++k) {
        int r = k * 4 + r0;
        tl[r][c] = in[(size_t)r * 2304 + c];
    }
    __syncthreads();
#pragma unroll
    for (int k = 0; k < 16; ++k) {
        int r2 = k * 4 + r0;
        outp[(size_t)r2 * 2048 + c] = tl[c][r2];
    }
}

// ---------------- GEMM: C[4096][N] = A[4096][768] @ BT[N][768] + bias ----------------
template <int BM, bool QKV>
__global__ __launch_bounds__(256) void k_gemm(const unsigned short* __restrict__ A,
                                              const unsigned short* __restrict__ BT,
                                              const float* __restrict__ b0,
                                              const float* __restrict__ b1,
                                              const float* __restrict__ b2,
                                              unsigned short* __restrict__ outb,
                                              float* __restrict__ outf) {
    constexpr int WM = BM / 2;
    constexpr int WR = WM / 16;
    constexpr int LDC = QKV ? 2304 : 768;
    __shared__ alignas(16) unsigned short As[BM][40];
    __shared__ alignas(16) unsigned short Bs[64][40];
    const int t = threadIdx.x;
    const int w = t >> 6, l = t & 63, lr = l & 15, lg = l >> 4;
    const int wr = (w >> 1) * WM, wc = (w & 1) * 32;
    const int m0 = blockIdx.y * BM;
    const int n0 = blockIdx.x * 64;

    f32x4 acc[WR][2] = {};

    for (int kt = 0; kt < 24; ++kt) {
        const int k0 = kt * 32;
        __syncthreads();
#pragma unroll
        for (int i = 0; i < BM / 64; ++i) {
            const int s = t + i * 256;
            *(uint4*)&As[s >> 2][(s & 3) * 8] =
                *(const uint4*)(A + (size_t)(m0 + (s >> 2)) * 768 + k0 + (s & 3) * 8);
        }
        *(uint4*)&Bs[t >> 2][(t & 3) * 8] =
            *(const uint4*)(BT + (size_t)(n0 + (t >> 2)) * 768 + k0 + (t & 3) * 8);
        __syncthreads();

        bf16x8 af[WR], bfr[2];
#pragma unroll
        for (int ri = 0; ri < WR; ++ri)
            af[ri] = *(const bf16x8*)&As[wr + ri * 16 + lr][lg * 8];
#pragma unroll
        for (int cj = 0; cj < 2; ++cj)
            bfr[cj] = *(const bf16x8*)&Bs[wc + cj * 16 + lr][lg * 8];
        __builtin_amdgcn_s_setprio(1);
#pragma unroll
        for (int ri = 0; ri < WR; ++ri)
#pragma unroll
            for (int cj = 0; cj < 2; ++cj)
                acc[ri][cj] = __builtin_amdgcn_mfma_f32_16x16x32_bf16(
                    af[ri], bfr[cj], acc[ri][cj], 0, 0, 0);
        __builtin_amdgcn_s_setprio(0);
    }

#pragma unroll
    for (int cj = 0; cj < 2; ++cj) {
        const int col = n0 + wc + cj * 16 + lr;
        const float* bp = b0;
        int cc = col;
        if (QKV) {
            if (col >= 1536)      { bp = b2; cc = col - 1536; }
            else if (col >= 768)  { bp = b1; cc = col - 768; }
        }
        const float bv = bp[cc];
        const float scl = (QKV && col < 768) ? 0.18033688011112042f : 1.0f;  // 0.125*log2e
#pragma unroll
        for (int ri = 0; ri < WR; ++ri)
#pragma unroll
            for (int e = 0; e < 4; ++e) {
                const int row = m0 + wr + ri * 16 + lg * 4 + e;
                const float v = (acc[ri][cj][e] + bv) * scl;
                if (QKV) outb[(size_t)row * LDC + col] = f32_bf16(v);
                else     outf[(size_t)row * LDC + col] = v;
            }
    }
}

// ---------------- flash attention, wave-split KV ----------------
// grid (hb=24, qv=64). qi = 63-qv (longest first). Block: 32 q-rows.
// Wave w handles kv tiles w, w+4, w+8, ... privately; merge at end via LDS.
// Per-wave LDS region WREG=8704 B: P tile [32][64] bf16 (4096B, swizzled) during the
// loop; o-merge [32][68] f32 (8704B) in the epilogue.
#define WREG 8704
__global__ __launch_bounds__(256) void k_flash(const unsigned short* __restrict__ qkv,
                                               const unsigned short* __restrict__ vtb,
                                               unsigned short* __restrict__ zb) {
    __shared__ alignas(16) char smem[4 * WREG + 1024];
    const int hb = blockIdx.x;              // 0..23
    const int h = hb % 12, b = hb / 12;
    const int qi = 63 - (int)blockIdx.y;
    const int q0 = qi * 32;
    const int t = threadIdx.x, w = t >> 6, l = t & 63, lr = l & 15, lg = l >> 4;
    const int nkv = (qi >> 1) + 1;

    __bf16* p_w = (__bf16*)(smem + w * WREG);
    float* mlds = (float*)(smem + 4 * WREG);          // [4][32]
    float* llds = (float*)(smem + 4 * WREG + 512);    // [4][32]

    const size_t qrowbase = (size_t)(b * 2048) * 2304;
    // Q fragments (A): rows q0+ri*16+lr, d = kk*32+lg*8..+7  (pre-scaled by 0.125*log2e)
    bf16x8 qf[2][2];
#pragma unroll
    for (int ri = 0; ri < 2; ++ri)
#pragma unroll
        for (int kk = 0; kk < 2; ++kk)
            qf[ri][kk] = *(const bf16x8*)(qkv + qrowbase + (size_t)(q0 + ri * 16 + lr) * 2304 +
                                          h * 64 + kk * 32 + lg * 8);

    f32x4 o[2][4] = {};
    f32x4 m2[2], ls[2];
#pragma unroll
    for (int ri = 0; ri < 2; ++ri)
#pragma unroll
        for (int e = 0; e < 4; ++e) { m2[ri][e] = -INFINITY; ls[ri][e] = 0.f; }

    const unsigned short* kb = qkv + qrowbase + 768 + h * 64;     // K cols
    const unsigned short* vt = vtb + (size_t)(b * 12 + h) * 64 * 2048;

    for (int kt = w; kt < nkv; kt += 4) {
        const int kv0 = kt * 64;
        // K fragments (B for QK^T): K rows kv0+cj*16+lr, d = kk*32+lg*8..+7
        bf16x8 kf[4][2];
#pragma unroll
        for (int cj = 0; cj < 4; ++cj)
#pragma unroll
            for (int kk = 0; kk < 2; ++kk)
                kf[cj][kk] = *(const bf16x8*)(kb + (size_t)(kv0 + cj * 16 + lr) * 2304 +
                                              kk * 32 + lg * 8);

        f32x4 sc[2][4];
        const f32x4 zz = {0.f, 0.f, 0.f, 0.f};
        __builtin_amdgcn_s_setprio(1);
#pragma unroll
        for (int ri = 0; ri < 2; ++ri)
#pragma unroll
            for (int cj = 0; cj < 4; ++cj) {
                f32x4 a0 = __builtin_amdgcn_mfma_f32_16x16x32_bf16(qf[ri][0], kf[cj][0], zz, 0, 0, 0);
                sc[ri][cj] = __builtin_amdgcn_mfma_f32_16x16x32_bf16(qf[ri][1], kf[cj][1], a0, 0, 0, 0);
            }
        __builtin_amdgcn_s_setprio(0);

        // V fragments (B for PV): V^T rows d=dj*16+lr, kv = kv0+kk*32+lg*8..+7.
        // Issued here so HBM/L2 latency hides under the softmax.
        bf16x8 vf[2][4];
#pragma unroll
        for (int kk = 0; kk < 2; ++kk)
#pragma unroll
            for (int dj = 0; dj < 4; ++dj)
                vf[kk][dj] = *(const bf16x8*)(vt + (size_t)(dj * 16 + lr) * 2048 +
                                              kv0 + kk * 32 + lg * 8);

        if (kt == nkv - 1) {  // diagonal tile
#pragma unroll
            for (int ri = 0; ri < 2; ++ri)
#pragma unroll
                for (int cj = 0; cj < 4; ++cj)
#pragma unroll
                    for (int e = 0; e < 4; ++e) {
                        const int row = q0 + ri * 16 + lg * 4 + e;
                        const int col = kv0 + cj * 16 + lr;
                        if (col > row) sc[ri][cj][e] = -1e30f;
                    }
        }

#pragma unroll
        for (int ri = 0; ri < 2; ++ri) {
            f32x4 mx;
#pragma unroll
            for (int e = 0; e < 4; ++e)
                mx[e] = fmaxf(fmaxf(sc[ri][0][e], sc[ri][1][e]),
                              fmaxf(sc[ri][2][e], sc[ri][3][e]));
#pragma unroll
            for (int msk = 1; msk < 16; msk <<= 1)
#pragma unroll
                for (int e = 0; e < 4; ++e) mx[e] = fmaxf(mx[e], __shfl_xor(mx[e], msk, 64));

            f32x4 m2n;
            bool grow = false;
#pragma unroll
            for (int e = 0; e < 4; ++e) {
                m2n[e] = fmaxf(m2[ri][e], mx[e]);
                grow |= (m2n[e] > m2[ri][e]);
            }
            if (__any(grow)) {
#pragma unroll
                for (int e = 0; e < 4; ++e) {
                    const float fs = __builtin_amdgcn_exp2f(m2[ri][e] - m2n[e]);
                    ls[ri][e] *= fs;
#pragma unroll
                    for (int dj = 0; dj < 4; ++dj) o[ri][dj][e] *= fs;
                    m2[ri][e] = m2n[e];
                }
            }

            f32x4 ps = {0.f, 0.f, 0.f, 0.f};
#pragma unroll
            for (int cj = 0; cj < 4; ++cj)
#pragma unroll
                for (int e = 0; e < 4; ++e) {
                    const float p = __builtin_amdgcn_exp2f(sc[ri][cj][e] - m2[ri][e]);
                    sc[ri][cj][e] = p;
                    ps[e] += p;
                }
#pragma unroll
            for (int msk = 1; msk < 16; msk <<= 1)
#pragma unroll
                for (int e = 0; e < 4; ++e) ps[e] += __shfl_xor(ps[e], msk, 64);
#pragma unroll
            for (int e = 0; e < 4; ++e) ls[ri][e] += ps[e];

            // P -> per-wave LDS, XOR-swizzled rows (stride 64 shorts = 128B)
#pragma unroll
            for (int cj = 0; cj < 4; ++cj)
#pragma unroll
                for (int e = 0; e < 4; ++e) {
                    const int row = ri * 16 + lg * 4 + e;
                    const int idx = row * 64 + (((cj * 2 + (lr >> 3)) ^ (row & 7)) << 3) + (lr & 7);
                    p_w[idx] = f32_bf16h(sc[ri][cj][e]);
                }
        }

        // fence: P-stores above must not be reordered past the pa loads below
        asm volatile("" ::: "memory");

        __builtin_amdgcn_s_setprio(1);
#pragma unroll
        for (int kk = 0; kk < 2; ++kk) {
            bf16x8 pa[2];
#pragma unroll
            for (int ri = 0; ri < 2; ++ri)
                pa[ri] = *(const bf16x8*)&p_w[(ri * 16 + lr) * 64 +
                                              (((kk * 4 + lg) ^ (lr & 7)) << 3)];
#pragma unroll
            for (int dj = 0; dj < 4; ++dj)
#pragma unroll
                for (int ri = 0; ri < 2; ++ri)
                    o[ri][dj] = __builtin_amdgcn_mfma_f32_16x16x32_bf16(
                        pa[ri], vf[kk][dj], o[ri][dj], 0, 0, 0);
        }
        __builtin_amdgcn_s_setprio(0);

        // fence: next iteration's P-stores must not be hoisted above the pa loads
        asm volatile("" ::: "memory");
    }

    // ---- in-block merge of 4 wave partials ----
    if (lr == 0) {
#pragma unroll
        for (int ri = 0; ri < 2; ++ri)
#pragma unroll
            for (int e = 0; e < 4; ++e) {
                const int row = ri * 16 + lg * 4 + e;
                mlds[w * 32 + row] = m2[ri][e];
                llds[w * 32 + row] = ls[ri][e];
            }
    }
    __syncthreads();

    float* o_w = (float*)(smem + w * WREG);  // [32][68] f32, reuses own p region
#pragma unroll
    for (int ri = 0; ri < 2; ++ri)
#pragma unroll
        for (int e = 0; e < 4; ++e) {
            const int row = ri * 16 + lg * 4 + e;
            float mg = fmaxf(fmaxf(mlds[row], mlds[32 + row]),
                             fmaxf(mlds[64 + row], mlds[96 + row]));
            const float f = __builtin_amdgcn_exp2f(m2[ri][e] - mg);
#pragma unroll
            for (int dj = 0; dj < 4; ++dj)
                o_w[row * 68 + dj * 16 + lr] = o[ri][dj][e] * f;
        }
    __syncthreads();

    {
        const int row = w * 8 + (l >> 3);
        const int c0 = (l & 7) * 8;
        const float mg = fmaxf(fmaxf(mlds[row], mlds[32 + row]),
                               fmaxf(mlds[64 + row], mlds[96 + row]));
        float lt = 0.f;
#pragma unroll
        for (int s = 0; s < 4; ++s)
            lt += __builtin_amdgcn_exp2f(mlds[s * 32 + row] - mg) * llds[s * 32 + row];
        const float inv = 1.0f / lt;
        ushort4 pk[2];
#pragma unroll
        for (int half = 0; half < 2; ++half) {
            unsigned short u[4];
#pragma unroll
            for (int k = 0; k < 4; ++k) {
                float acc = 0.f;
#pragma unroll
                for (int s = 0; s < 4; ++s)
                    acc += ((const float*)(smem + s * WREG))[row * 68 + c0 + half * 4 + k];
                u[k] = f32_bf16(acc * inv);
            }
            pk[half] = make_ushort4(u[0], u[1], u[2], u[3]);
        }
        unsigned short* dst = zb + (size_t)(b * 2048 + q0 + row) * 768 + h * 64 + c0;
        *(ushort4*)dst = pk[0];
        *(ushort4*)(dst + 4) = pk[1];
    }
}

extern "C" void kernel_launch(void* const* d_in, const int* in_sizes, int n_in,
                              void* d_out, int out_size, void* d_ws, size_t ws_size,
                              hipStream_t stream) {
    (void)in_sizes; (void)n_in; (void)out_size; (void)ws_size;
    const float* x   = (const float*)d_in[0];
    const float* W_Q = (const float*)d_in[1];
    const float* W_K = (const float*)d_in[2];
    const float* W_V = (const float*)d_in[3];
    const float* b_Q = (const float*)d_in[4];
    const float* b_K = (const float*)d_in[5];
    const float* b_V = (const float*)d_in[6];
    const float* W_O = (const float*)d_in[7];
    const float* b_O = (const float*)d_in[8];
    float* out = (float*)d_out;

    char* ws = (char*)d_ws;
    unsigned short* xb    = (unsigned short*)(ws);
    unsigned short* qkvb  = (unsigned short*)(ws + 6291456);
    unsigned short* vtb   = (unsigned short*)(ws + 25165824);
    unsigned short* wqkvT = (unsigned short*)(ws + 31457280);
    unsigned short* woT   = (unsigned short*)(ws + 34996224);
    unsigned short* zb    = xb;  // xb dead after the QKV GEMM

    k_convert<<<3072, 256, 0, stream>>>(x, xb);
    k_transpose_wqkv<<<dim3(12, 36), 256, 0, stream>>>(W_Q, W_K, W_V, wqkvT);
    k_transpose_w<<<dim3(144, 1), 256, 0, stream>>>(W_O, woT, 768, 768, 12);

    k_gemm<128, true><<<dim3(36, 32), 256, 0, stream>>>(xb, wqkvT, b_Q, b_K, b_V, qkvb, nullptr);

    k_transpose_v<<<dim3(32, 24), 256, 0, stream>>>(qkvb + 1536, vtb);
    k_flash<<<dim3(24, 64), 256, 0, stream>>>(qkvb, vtb, zb);
    k_gemm<64, false><<<dim3(12, 64), 256, 0, stream>>>(zb, woT, b_O, b_O, b_O, nullptr, out);
}

// Round 6
// 134.243 us; speedup vs baseline: 1.5868x; 1.0077x over previous
//
#include <hip/hip_runtime.h>

// Fused causal MHA on gfx950.  Pipeline (R5 = R4 + BN=128 GEMMs + cvt_pk P-pack):
//   k_convert:        x fp32 -> xb bf16                         [4096][768]
//   k_transpose_wqkv: W_Q|W_K|W_V fp32 [h][768][64] -> wqkvT bf16 [2304][768]
//   k_transpose_w:    W_O fp32 [768][768] -> woT bf16 [768][768]^T
//   k_gemm<true>:     qkvb bf16 [4096][2304] = xb @ wqkvT^T + bias (Q cols pre-scaled
//                     by 0.125*log2e).  BM=128 BN=128 BK=32, wave-tile 64x64.
//   k_transpose_v:    qkvb(v cols) -> vtb [24][64][2048]
//   k_flash:          QBLK=32, 4 waves SPLIT the KV range (wave w: tiles w,w+4,..),
//                     private (m,l,o) partials, in-block LDS merge, no in-loop barriers.
//                     P-pack via v_cvt_pk_bf16_f32 (2 elems/inst).
//   k_gemm<false>:    d_out fp32 = zb @ woT^T + b_O
//
// ws: xb/zb @0 (6291456) | qkvb @6291456 (18874368) | vtb @25165824 (6291456)
//     wqkvT @31457280 (3538944) | woT @34996224 (1179648)   total 36175872 B

#define DEVINL __device__ __forceinline__

using bf16x8 = __attribute__((ext_vector_type(8))) __bf16;
using f32x4  = __attribute__((ext_vector_type(4))) float;

DEVINL unsigned short f32_bf16(float f) {
    unsigned u = __builtin_bit_cast(unsigned, f);
    return (unsigned short)((u + 0x7FFFu + ((u >> 16) & 1u)) >> 16);
}

// ---------------- convert fp32 -> bf16, 4 elems/thread ----------------
__global__ __launch_bounds__(256) void k_convert(const float* __restrict__ in,
                                                 unsigned short* __restrict__ out) {
    int i = (blockIdx.x * 256 + threadIdx.x) * 4;
    float4 v = *(const float4*)(in + i);
    ushort4 o;
    o.x = f32_bf16(v.x); o.y = f32_bf16(v.y); o.z = f32_bf16(v.z); o.w = f32_bf16(v.w);
    *(ushort4*)(out + i) = o;
}

// ---------------- transpose + convert: in fp32 [R][C] -> out bf16 [C][R], batched ----
__global__ __launch_bounds__(256) void k_transpose_w(const float* __restrict__ in,
                                                     unsigned short* __restrict__ out,
                                                     int R, int C, int tilesR) {
    __shared__ unsigned short tl[64][68];
    const int batch = blockIdx.y;
    const int tr = blockIdx.x % tilesR, tc = blockIdx.x / tilesR;
    in  += (size_t)batch * R * C;
    out += (size_t)batch * R * C;
    const int t = threadIdx.x, c = t & 63, r0 = t >> 6;
#pragma unroll
    for (int k = 0; k < 16; ++k) {
        int r = k * 4 + r0;
        tl[r][c] = f32_bf16(in[(size_t)(tr * 64 + r) * C + tc * 64 + c]);
    }
    __syncthreads();
#pragma unroll
    for (int k = 0; k < 16; ++k) {
        int r2 = k * 4 + r0;
        out[(size_t)(tc * 64 + r2) * R + tr * 64 + c] = tl[c][r2];
    }
}

// ---------------- fused W_Q/W_K/W_V transpose -> wqkvT [2304][768] ----------------
__global__ __launch_bounds__(256) void k_transpose_wqkv(const float* __restrict__ Wq,
                                                        const float* __restrict__ Wk,
                                                        const float* __restrict__ Wv,
                                                        unsigned short* __restrict__ out) {
    __shared__ unsigned short tl[64][68];
    const int batch = blockIdx.y;               // 0..35
    const int tr = blockIdx.x;                  // 0..11 (768/64)
    const float* src = (batch < 12) ? Wq : (batch < 24) ? Wk : Wv;
    src += (size_t)(batch % 12) * 768 * 64;
    out += (size_t)batch * 64 * 768;
    const int t = threadIdx.x, c = t & 63, r0 = t >> 6;
#pragma unroll
    for (int k = 0; k < 16; ++k) {
        int r = k * 4 + r0;
        tl[r][c] = f32_bf16(src[(size_t)(tr * 64 + r) * 64 + c]);
    }
    __syncthreads();
#pragma unroll
    for (int k = 0; k < 16; ++k) {
        int r2 = k * 4 + r0;
        out[(size_t)r2 * 768 + tr * 64 + c] = tl[c][r2];
    }
}

// ---------------- transpose V: qkvb v-cols [b,s,2304] -> vtb [b*12+h][64][2048] -------
__global__ __launch_bounds__(256) void k_transpose_v(const unsigned short* __restrict__ vb,
                                                     unsigned short* __restrict__ vtb) {
    __shared__ unsigned short tl[64][68];
    const int bh = blockIdx.y;
    const int s0 = blockIdx.x * 64;
    const unsigned short* in = vb + ((size_t)((bh / 12) * 2048 + s0)) * 2304 + (bh % 12) * 64;
    unsigned short* outp = vtb + (size_t)bh * 64 * 2048 + s0;
    const int t = threadIdx.x, c = t & 63, r0 = t >> 6;
#pragma unroll
    for (int k = 0; k < 16; ++k) {
        int r = k * 4 + r0;
        tl[r][c] = in[(size_t)r * 2304 + c];
    }
    __syncthreads();
#pragma unroll
    for (int k = 0; k < 16; ++k) {
        int r2 = k * 4 + r0;
        outp[(size_t)r2 * 2048 + c] = tl[c][r2];
    }
}

// ---------------- GEMM: C[4096][N] = A[4096][768] @ BT[N][768] + bias ----------------
// BM=128 BN=128 BK=32, 256 thr = 4 waves in 2x2, wave tile 64x64 (acc 4x4),
// 16 MFMA per k-step per wave.
template <bool QKV>
__global__ __launch_bounds__(256) void k_gemm(const unsigned short* __restrict__ A,
                                              const unsigned short* __restrict__ BT,
                                              const float* __restrict__ b0,
                                              const float* __restrict__ b1,
                                              const float* __restrict__ b2,
                                              unsigned short* __restrict__ outb,
                                              float* __restrict__ outf) {
    constexpr int LDC = QKV ? 2304 : 768;
    __shared__ alignas(16) unsigned short As[128][40];
    __shared__ alignas(16) unsigned short Bs[128][40];
    const int t = threadIdx.x;
    const int w = t >> 6, l = t & 63, lr = l & 15, lg = l >> 4;
    const int wr = (w >> 1) * 64, wc = (w & 1) * 64;
    const int m0 = blockIdx.y * 128;
    const int n0 = blockIdx.x * 128;

    f32x4 acc[4][4] = {};

    for (int kt = 0; kt < 24; ++kt) {
        const int k0 = kt * 32;
        __syncthreads();
#pragma unroll
        for (int i = 0; i < 2; ++i) {
            const int s = t + i * 256;
            *(uint4*)&As[s >> 2][(s & 3) * 8] =
                *(const uint4*)(A + (size_t)(m0 + (s >> 2)) * 768 + k0 + (s & 3) * 8);
            *(uint4*)&Bs[s >> 2][(s & 3) * 8] =
                *(const uint4*)(BT + (size_t)(n0 + (s >> 2)) * 768 + k0 + (s & 3) * 8);
        }
        __syncthreads();

        bf16x8 af[4], bfr[4];
#pragma unroll
        for (int ri = 0; ri < 4; ++ri)
            af[ri] = *(const bf16x8*)&As[wr + ri * 16 + lr][lg * 8];
#pragma unroll
        for (int cj = 0; cj < 4; ++cj)
            bfr[cj] = *(const bf16x8*)&Bs[wc + cj * 16 + lr][lg * 8];
        __builtin_amdgcn_s_setprio(1);
#pragma unroll
        for (int ri = 0; ri < 4; ++ri)
#pragma unroll
            for (int cj = 0; cj < 4; ++cj)
                acc[ri][cj] = __builtin_amdgcn_mfma_f32_16x16x32_bf16(
                    af[ri], bfr[cj], acc[ri][cj], 0, 0, 0);
        __builtin_amdgcn_s_setprio(0);
    }

#pragma unroll
    for (int cj = 0; cj < 4; ++cj) {
        const int col = n0 + wc + cj * 16 + lr;
        const float* bp = b0;
        int cc = col;
        if (QKV) {
            if (col >= 1536)      { bp = b2; cc = col - 1536; }
            else if (col >= 768)  { bp = b1; cc = col - 768; }
        }
        const float bv = bp[cc];
        const float scl = (QKV && col < 768) ? 0.18033688011112042f : 1.0f;  // 0.125*log2e
#pragma unroll
        for (int ri = 0; ri < 4; ++ri)
#pragma unroll
            for (int e = 0; e < 4; ++e) {
                const int row = m0 + wr + ri * 16 + lg * 4 + e;
                const float v = (acc[ri][cj][e] + bv) * scl;
                if (QKV) outb[(size_t)row * LDC + col] = f32_bf16(v);
                else     outf[(size_t)row * LDC + col] = v;
            }
    }
}

// ---------------- flash attention, wave-split KV ----------------
// grid (hb=24, qv=64). qi = 63-qv (longest first). Block: 32 q-rows.
// Wave w handles kv tiles w, w+4, w+8, ... privately; merge at end via LDS.
// Per-wave LDS region WREG=8704 B: P tile [32][64] bf16 (4096B, swizzled) during the
// loop; o-merge [32][68] f32 (8704B) in the epilogue.
#define WREG 8704
__global__ __launch_bounds__(256) void k_flash(const unsigned short* __restrict__ qkv,
                                               const unsigned short* __restrict__ vtb,
                                               unsigned short* __restrict__ zb) {
    __shared__ alignas(16) char smem[4 * WREG + 1024];
    const int hb = blockIdx.x;              // 0..23
    const int h = hb % 12, b = hb / 12;
    const int qi = 63 - (int)blockIdx.y;
    const int q0 = qi * 32;
    const int t = threadIdx.x, w = t >> 6, l = t & 63, lr = l & 15, lg = l >> 4;
    const int nkv = (qi >> 1) + 1;

    __bf16* p_w = (__bf16*)(smem + w * WREG);
    float* mlds = (float*)(smem + 4 * WREG);          // [4][32]
    float* llds = (float*)(smem + 4 * WREG + 512);    // [4][32]

    const size_t qrowbase = (size_t)(b * 2048) * 2304;
    // Q fragments (A): rows q0+ri*16+lr, d = kk*32+lg*8..+7  (pre-scaled by 0.125*log2e)
    bf16x8 qf[2][2];
#pragma unroll
    for (int ri = 0; ri < 2; ++ri)
#pragma unroll
        for (int kk = 0; kk < 2; ++kk)
            qf[ri][kk] = *(const bf16x8*)(qkv + qrowbase + (size_t)(q0 + ri * 16 + lr) * 2304 +
                                          h * 64 + kk * 32 + lg * 8);

    f32x4 o[2][4] = {};
    f32x4 m2[2], ls[2];
#pragma unroll
    for (int ri = 0; ri < 2; ++ri)
#pragma unroll
        for (int e = 0; e < 4; ++e) { m2[ri][e] = -INFINITY; ls[ri][e] = 0.f; }

    const unsigned short* kb = qkv + qrowbase + 768 + h * 64;     // K cols
    const unsigned short* vt = vtb + (size_t)(b * 12 + h) * 64 * 2048;

    for (int kt = w; kt < nkv; kt += 4) {
        const int kv0 = kt * 64;
        // K fragments (B for QK^T): K rows kv0+cj*16+lr, d = kk*32+lg*8..+7
        bf16x8 kf[4][2];
#pragma unroll
        for (int cj = 0; cj < 4; ++cj)
#pragma unroll
            for (int kk = 0; kk < 2; ++kk)
                kf[cj][kk] = *(const bf16x8*)(kb + (size_t)(kv0 + cj * 16 + lr) * 2304 +
                                              kk * 32 + lg * 8);

        f32x4 sc[2][4];
        const f32x4 zz = {0.f, 0.f, 0.f, 0.f};
        __builtin_amdgcn_s_setprio(1);
#pragma unroll
        for (int ri = 0; ri < 2; ++ri)
#pragma unroll
            for (int cj = 0; cj < 4; ++cj) {
                f32x4 a0 = __builtin_amdgcn_mfma_f32_16x16x32_bf16(qf[ri][0], kf[cj][0], zz, 0, 0, 0);
                sc[ri][cj] = __builtin_amdgcn_mfma_f32_16x16x32_bf16(qf[ri][1], kf[cj][1], a0, 0, 0, 0);
            }
        __builtin_amdgcn_s_setprio(0);

        // V fragments (B for PV): V^T rows d=dj*16+lr, kv = kv0+kk*32+lg*8..+7.
        // Issued here so HBM/L2 latency hides under the softmax.
        bf16x8 vf[2][4];
#pragma unroll
        for (int kk = 0; kk < 2; ++kk)
#pragma unroll
            for (int dj = 0; dj < 4; ++dj)
                vf[kk][dj] = *(const bf16x8*)(vt + (size_t)(dj * 16 + lr) * 2048 +
                                              kv0 + kk * 32 + lg * 8);

        if (kt == nkv - 1) {  // diagonal tile
#pragma unroll
            for (int ri = 0; ri < 2; ++ri)
#pragma unroll
                for (int cj = 0; cj < 4; ++cj)
#pragma unroll
                    for (int e = 0; e < 4; ++e) {
                        const int row = q0 + ri * 16 + lg * 4 + e;
                        const int col = kv0 + cj * 16 + lr;
                        if (col > row) sc[ri][cj][e] = -1e30f;
                    }
        }

#pragma unroll
        for (int ri = 0; ri < 2; ++ri) {
            f32x4 mx;
#pragma unroll
            for (int e = 0; e < 4; ++e)
                mx[e] = fmaxf(fmaxf(sc[ri][0][e], sc[ri][1][e]),
                              fmaxf(sc[ri][2][e], sc[ri][3][e]));
#pragma unroll
            for (int msk = 1; msk < 16; msk <<= 1)
#pragma unroll
                for (int e = 0; e < 4; ++e) mx[e] = fmaxf(mx[e], __shfl_xor(mx[e], msk, 64));

            f32x4 m2n;
            bool grow = false;
#pragma unroll
            for (int e = 0; e < 4; ++e) {
                m2n[e] = fmaxf(m2[ri][e], mx[e]);
                grow |= (m2n[e] > m2[ri][e]);
            }
            if (__any(grow)) {
#pragma unroll
                for (int e = 0; e < 4; ++e) {
                    const float fs = __builtin_amdgcn_exp2f(m2[ri][e] - m2n[e]);
                    ls[ri][e] *= fs;
#pragma unroll
                    for (int dj = 0; dj < 4; ++dj) o[ri][dj][e] *= fs;
                    m2[ri][e] = m2n[e];
                }
            }

            f32x4 ps = {0.f, 0.f, 0.f, 0.f};
#pragma unroll
            for (int cj = 0; cj < 4; ++cj)
#pragma unroll
                for (int e = 0; e < 4; ++e) {
                    const float p = __builtin_amdgcn_exp2f(sc[ri][cj][e] - m2[ri][e]);
                    sc[ri][cj][e] = p;
                    ps[e] += p;
                }
#pragma unroll
            for (int msk = 1; msk < 16; msk <<= 1)
#pragma unroll
                for (int e = 0; e < 4; ++e) ps[e] += __shfl_xor(ps[e], msk, 64);
#pragma unroll
            for (int e = 0; e < 4; ++e) ls[ri][e] += ps[e];

            // P -> per-wave LDS, XOR-swizzled rows (stride 64 shorts = 128B).
            // v_cvt_pk_bf16_f32 packs two f32->bf16 (RNE, bit-identical to f32_bf16).
#pragma unroll
            for (int cj = 0; cj < 4; cj += 2)
#pragma unroll
                for (int e = 0; e < 4; ++e) {
                    unsigned pk;
                    asm("v_cvt_pk_bf16_f32 %0, %1, %2"
                        : "=v"(pk) : "v"(sc[ri][cj][e]), "v"(sc[ri][cj + 1][e]));
                    const int row = ri * 16 + lg * 4 + e;
                    const int i0 = row * 64 + (((cj * 2 + (lr >> 3)) ^ (row & 7)) << 3) + (lr & 7);
                    const int i1 = row * 64 + ((((cj + 1) * 2 + (lr >> 3)) ^ (row & 7)) << 3) + (lr & 7);
                    p_w[i0] = __builtin_bit_cast(__bf16, (unsigned short)(pk & 0xffffu));
                    p_w[i1] = __builtin_bit_cast(__bf16, (unsigned short)(pk >> 16));
                }
        }

        // fence: P-stores above must not be reordered past the pa loads below
        asm volatile("" ::: "memory");

        __builtin_amdgcn_s_setprio(1);
#pragma unroll
        for (int kk = 0; kk < 2; ++kk) {
            bf16x8 pa[2];
#pragma unroll
            for (int ri = 0; ri < 2; ++ri)
                pa[ri] = *(const bf16x8*)&p_w[(ri * 16 + lr) * 64 +
                                              (((kk * 4 + lg) ^ (lr & 7)) << 3)];
#pragma unroll
            for (int dj = 0; dj < 4; ++dj)
#pragma unroll
                for (int ri = 0; ri < 2; ++ri)
                    o[ri][dj] = __builtin_amdgcn_mfma_f32_16x16x32_bf16(
                        pa[ri], vf[kk][dj], o[ri][dj], 0, 0, 0);
        }
        __builtin_amdgcn_s_setprio(0);

        // fence: next iteration's P-stores must not be hoisted above the pa loads
        asm volatile("" ::: "memory");
    }

    // ---- in-block merge of 4 wave partials ----
    if (lr == 0) {
#pragma unroll
        for (int ri = 0; ri < 2; ++ri)
#pragma unroll
            for (int e = 0; e < 4; ++e) {
                const int row = ri * 16 + lg * 4 + e;
                mlds[w * 32 + row] = m2[ri][e];
                llds[w * 32 + row] = ls[ri][e];
            }
    }
    __syncthreads();

    float* o_w = (float*)(smem + w * WREG);  // [32][68] f32, reuses own p region
#pragma unroll
    for (int ri = 0; ri < 2; ++ri)
#pragma unroll
        for (int e = 0; e < 4; ++e) {
            const int row = ri * 16 + lg * 4 + e;
            float mg = fmaxf(fmaxf(mlds[row], mlds[32 + row]),
                             fmaxf(mlds[64 + row], mlds[96 + row]));
            const float f = __builtin_amdgcn_exp2f(m2[ri][e] - mg);
#pragma unroll
            for (int dj = 0; dj < 4; ++dj)
                o_w[row * 68 + dj * 16 + lr] = o[ri][dj][e] * f;
        }
    __syncthreads();

    {
        const int row = w * 8 + (l >> 3);
        const int c0 = (l & 7) * 8;
        const float mg = fmaxf(fmaxf(mlds[row], mlds[32 + row]),
                               fmaxf(mlds[64 + row], mlds[96 + row]));
        float lt = 0.f;
#pragma unroll
        for (int s = 0; s < 4; ++s)
            lt += __builtin_amdgcn_exp2f(mlds[s * 32 + row] - mg) * llds[s * 32 + row];
        const float inv = 1.0f / lt;
        ushort4 pk[2];
#pragma unroll
        for (int half = 0; half < 2; ++half) {
            unsigned short u[4];
#pragma unroll
            for (int k = 0; k < 4; ++k) {
                float acc = 0.f;
#pragma unroll
                for (int s = 0; s < 4; ++s)
                    acc += ((const float*)(smem + s * WREG))[row * 68 + c0 + half * 4 + k];
                u[k] = f32_bf16(acc * inv);
            }
            pk[half] = make_ushort4(u[0], u[1], u[2], u[3]);
        }
        unsigned short* dst = zb + (size_t)(b * 2048 + q0 + row) * 768 + h * 64 + c0;
        *(ushort4*)dst = pk[0];
        *(ushort4*)(dst + 4) = pk[1];
    }
}

extern "C" void kernel_launch(void* const* d_in, const int* in_sizes, int n_in,
                              void* d_out, int out_size, void* d_ws, size_t ws_size,
                              hipStream_t stream) {
    (void)in_sizes; (void)n_in; (void)out_size; (void)ws_size;
    const float* x   = (const float*)d_in[0];
    const float* W_Q = (const float*)d_in[1];
    const float* W_K = (const float*)d_in[2];
    const float* W_V = (const float*)d_in[3];
    const float* b_Q = (const float*)d_in[4];
    const float* b_K = (const float*)d_in[5];
    const float* b_V = (const float*)d_in[6];
    const float* W_O = (const float*)d_in[7];
    const float* b_O = (const float*)d_in[8];
    float* out = (float*)d_out;

    char* ws = (char*)d_ws;
    unsigned short* xb    = (unsigned short*)(ws);
    unsigned short* qkvb  = (unsigned short*)(ws + 6291456);
    unsigned short* vtb   = (unsigned short*)(ws + 25165824);
    unsigned short* wqkvT = (unsigned short*)(ws + 31457280);
    unsigned short* woT   = (unsigned short*)(ws + 34996224);
    unsigned short* zb    = xb;  // xb dead after the QKV GEMM

    k_convert<<<3072, 256, 0, stream>>>(x, xb);
    k_transpose_wqkv<<<dim3(12, 36), 256, 0, stream>>>(W_Q, W_K, W_V, wqkvT);
    k_transpose_w<<<dim3(144, 1), 256, 0, stream>>>(W_O, woT, 768, 768, 12);

    k_gemm<true><<<dim3(18, 32), 256, 0, stream>>>(xb, wqkvT, b_Q, b_K, b_V, qkvb, nullptr);

    k_transpose_v<<<dim3(32, 24), 256, 0, stream>>>(qkvb + 1536, vtb);
    k_flash<<<dim3(24, 64), 256, 0, stream>>>(qkvb, vtb, zb);
    k_gemm<false><<<dim3(6, 32), 256, 0, stream>>>(zb, woT, b_O, b_O, b_O, nullptr, out);
}

// Round 7
// 132.147 us; speedup vs baseline: 1.6120x; 1.0159x over previous
//
#include <hip/hip_runtime.h>

// Fused causal MHA on gfx950.  Pipeline (R6):
//   k_prep:        x fp32 -> xb bf16 ; W_Q|W_K|W_V -> wqkvT bf16 [2304][768] ;
//                  W_O -> woT bf16 [768][768]^T     (one kernel, 3 job ranges)
//   k_gemm<128,128,true>:  qkvb bf16 [4096][2304] = xb @ wqkvT^T + bias
//                  (Q cols pre-scaled by 0.125*log2e; global_load_lds staging)
//   k_transpose_v: qkvb(v cols) -> vtb [24][64][2048]
//   k_flash:       QBLK=32, 4 waves split KV range, swapped-operand softmax:
//                  QK^T computed as mfma(K,Q)=S^T (q = lane&15), PV as
//                  mfma(V^T,P)=O^T -> scalar m/l per lane, 2-step shfl reduces.
//   k_gemm<64,64,false>:   d_out fp32 = zb @ woT^T + b_O
//
// ws: xb/zb @0 (6291456) | qkvb @6291456 (18874368) | vtb @25165824 (6291456)
//     wqkvT @31457280 (3538944) | woT @34996224 (1179648)   total 36175872 B

#define DEVINL __device__ __forceinline__

using bf16x8 = __attribute__((ext_vector_type(8))) __bf16;
using f32x4  = __attribute__((ext_vector_type(4))) float;

DEVINL unsigned short f32_bf16(float f) {
    unsigned u = __builtin_bit_cast(unsigned, f);
    return (unsigned short)((u + 0x7FFFu + ((u >> 16) & 1u)) >> 16);
}

DEVINL void gload16(const void* g, void* l) {
    __builtin_amdgcn_global_load_lds(
        (const __attribute__((address_space(1))) void*)g,
        (__attribute__((address_space(3))) void*)l, 16, 0, 0);
}

// ---------------- fused prep: convert + weight transposes ----------------
// blocks [0,3072): convert x; [3072,3504): wqkv transpose; [3504,3648): W_O transpose.
__global__ __launch_bounds__(256) void k_prep(const float* __restrict__ x,
                                              const float* __restrict__ Wq,
                                              const float* __restrict__ Wk,
                                              const float* __restrict__ Wv,
                                              const float* __restrict__ Wo,
                                              unsigned short* __restrict__ xb,
                                              unsigned short* __restrict__ wqkvT,
                                              unsigned short* __restrict__ woT) {
    __shared__ unsigned short tl[64][68];
    const int bid = blockIdx.x;
    const int t = threadIdx.x;
    if (bid < 3072) {
        int i = (bid * 256 + t) * 4;
        float4 v = *(const float4*)(x + i);
        ushort4 o;
        o.x = f32_bf16(v.x); o.y = f32_bf16(v.y); o.z = f32_bf16(v.z); o.w = f32_bf16(v.w);
        *(ushort4*)(xb + i) = o;
        return;
    }
    const int c = t & 63, r0 = t >> 6;
    if (bid < 3504) {
        const int sub = bid - 3072;          // 0..431
        const int tr = sub % 12, batch = sub / 12;   // batch 0..35
        const float* src = (batch < 12) ? Wq : (batch < 24) ? Wk : Wv;
        src += (size_t)(batch % 12) * 768 * 64;
        unsigned short* out = wqkvT + (size_t)batch * 64 * 768;
#pragma unroll
        for (int k = 0; k < 16; ++k) {
            int r = k * 4 + r0;
            tl[r][c] = f32_bf16(src[(size_t)(tr * 64 + r) * 64 + c]);
        }
        __syncthreads();
#pragma unroll
        for (int k = 0; k < 16; ++k) {
            int r2 = k * 4 + r0;
            out[(size_t)r2 * 768 + tr * 64 + c] = tl[c][r2];
        }
    } else {
        const int sub = bid - 3504;          // 0..143
        const int tr = sub % 12, tc = sub / 12;
#pragma unroll
        for (int k = 0; k < 16; ++k) {
            int r = k * 4 + r0;
            tl[r][c] = f32_bf16(Wo[(size_t)(tr * 64 + r) * 768 + tc * 64 + c]);
        }
        __syncthreads();
#pragma unroll
        for (int k = 0; k < 16; ++k) {
            int r2 = k * 4 + r0;
            woT[(size_t)(tc * 64 + r2) * 768 + tr * 64 + c] = tl[c][r2];
        }
    }
}

// ---------------- transpose V: qkvb v-cols [b,s,2304] -> vtb [b*12+h][64][2048] -------
__global__ __launch_bounds__(256) void k_transpose_v(const unsigned short* __restrict__ vb,
                                                     unsigned short* __restrict__ vtb) {
    __shared__ unsigned short tl[64][68];
    const int bh = blockIdx.y;
    const int s0 = blockIdx.x * 64;
    const unsigned short* in = vb + ((size_t)((bh / 12) * 2048 + s0)) * 2304 + (bh % 12) * 64;
    unsigned short* outp = vtb + (size_t)bh * 64 * 2048 + s0;
    const int t = threadIdx.x, c = t & 63, r0 = t >> 6;
#pragma unroll
    for (int k = 0; k < 16; ++k) {
        int r = k * 4 + r0;
        tl[r][c] = in[(size_t)r * 2304 + c];
    }
    __syncthreads();
#pragma unroll
    for (int k = 0; k < 16; ++k) {
        int r2 = k * 4 + r0;
        outp[(size_t)r2 * 2048 + c] = tl[c][r2];
    }
}

// ---------------- GEMM: C[4096][N] = A[4096][768] @ BT[N][768] + bias ----------------
// m97 structure: unpadded LDS (64 B rows), global_load_lds width-16 staging,
// 2-barrier loop, 4 waves in 2x2.
template <int BM, int BN, bool QKV>
__global__ __launch_bounds__(256, 4) void k_gemm(const unsigned short* __restrict__ A,
                                                 const unsigned short* __restrict__ BT,
                                                 const float* __restrict__ b0,
                                                 const float* __restrict__ b1,
                                                 const float* __restrict__ b2,
                                                 unsigned short* __restrict__ outb,
                                                 float* __restrict__ outf) {
    constexpr int LDC = QKV ? 2304 : 768;
    constexpr int WM = BM / 2, WN = BN / 2, MR = WM / 16, NR = WN / 16;
    __shared__ alignas(16) unsigned short As[BM * 32];
    __shared__ alignas(16) unsigned short Bs[BN * 32];
    const int t = threadIdx.x;
    const int w = t >> 6, l = t & 63, lr = l & 15, lg = l >> 4;
    const int wr = (w >> 1) * WM, wc = (w & 1) * WN;
    const int m0 = blockIdx.y * BM;
    const int n0 = blockIdx.x * BN;

    f32x4 acc[MR][NR] = {};

    for (int kt = 0; kt < 24; ++kt) {
        const int k0 = kt * 32;
        __syncthreads();
#pragma unroll
        for (int i = 0; i < BM / 64; ++i) {
            const int s = i * 256 + t;
            gload16((const char*)A + ((size_t)(m0 + (s >> 2)) * 768 + k0) * 2 + (s & 3) * 16,
                    (char*)As + s * 16);
        }
#pragma unroll
        for (int i = 0; i < BN / 64; ++i) {
            const int s = i * 256 + t;
            gload16((const char*)BT + ((size_t)(n0 + (s >> 2)) * 768 + k0) * 2 + (s & 3) * 16,
                    (char*)Bs + s * 16);
        }
        __syncthreads();   // drains vmcnt(0): LDS tiles ready

        bf16x8 af[MR], bfr[NR];
#pragma unroll
        for (int ri = 0; ri < MR; ++ri)
            af[ri] = *(const bf16x8*)&As[(wr + ri * 16 + lr) * 32 + lg * 8];
#pragma unroll
        for (int cj = 0; cj < NR; ++cj)
            bfr[cj] = *(const bf16x8*)&Bs[(wc + cj * 16 + lr) * 32 + lg * 8];
        __builtin_amdgcn_s_setprio(1);
#pragma unroll
        for (int ri = 0; ri < MR; ++ri)
#pragma unroll
            for (int cj = 0; cj < NR; ++cj)
                acc[ri][cj] = __builtin_amdgcn_mfma_f32_16x16x32_bf16(
                    af[ri], bfr[cj], acc[ri][cj], 0, 0, 0);
        __builtin_amdgcn_s_setprio(0);
    }

#pragma unroll
    for (int cj = 0; cj < NR; ++cj) {
        const int col = n0 + wc + cj * 16 + lr;
        const float* bp = b0;
        int cc = col;
        if (QKV) {
            if (col >= 1536)      { bp = b2; cc = col - 1536; }
            else if (col >= 768)  { bp = b1; cc = col - 768; }
        }
        const float bv = bp[cc];
        const float scl = (QKV && col < 768) ? 0.18033688011112042f : 1.0f;  // 0.125*log2e
#pragma unroll
        for (int ri = 0; ri < MR; ++ri)
#pragma unroll
            for (int e = 0; e < 4; ++e) {
                const int row = m0 + wr + ri * 16 + lg * 4 + e;
                const float v = (acc[ri][cj][e] + bv) * scl;
                if (QKV) outb[(size_t)row * LDC + col] = f32_bf16(v);
                else     outf[(size_t)row * LDC + col] = v;
            }
    }
}

// ---------------- flash attention, wave-split KV, swapped-operand softmax -------------
// grid (hb=24, qv=64). qi = 63-qv (longest first). Block: 32 q-rows.
// Wave w handles kv tiles w, w+4, ... privately; merge at end via LDS.
// QK^T as mfma(K,Q)=S^T: lane holds 16 kv for fixed q=ri*16+lr -> scalar m/l,
// 15 in-lane fmax + 2 shfl steps.  PV as mfma(V^T,P)=O^T so o's q axis = lr too.
// Per-wave LDS region WREG: P tile [32 q][64 kv] bf16 (4096 B, XOR-swizzled 16B
// granules) during loop; o-merge [32][72] f32 (9216 B) in epilogue.
#define WREG 9216
__global__ __launch_bounds__(256, 4) void k_flash(const unsigned short* __restrict__ qkv,
                                                  const unsigned short* __restrict__ vtb,
                                                  unsigned short* __restrict__ zb) {
    __shared__ alignas(16) char smem[4 * WREG + 1024];
    const int hb = blockIdx.x;              // 0..23
    const int h = hb % 12, b = hb / 12;
    const int qi = 63 - (int)blockIdx.y;
    const int q0 = qi * 32;
    const int t = threadIdx.x, w = t >> 6, l = t & 63, lr = l & 15, lg = l >> 4;
    const int nkv = (qi >> 1) + 1;

    char* p_w = smem + w * WREG;                      // P[q][kv] bf16, swizzled
    float* mlds = (float*)(smem + 4 * WREG);          // [4][32]
    float* llds = (float*)(smem + 4 * WREG + 512);    // [4][32]

    const size_t qrowbase = (size_t)(b * 2048) * 2304;
    // Q fragments (B-operand now): Q[q0+ri*16+lr][kk*32+lg*8..] (pre-scaled)
    bf16x8 qf[2][2];
#pragma unroll
    for (int ri = 0; ri < 2; ++ri)
#pragma unroll
        for (int kk = 0; kk < 2; ++kk)
            qf[ri][kk] = *(const bf16x8*)(qkv + qrowbase + (size_t)(q0 + ri * 16 + lr) * 2304 +
                                          h * 64 + kk * 32 + lg * 8);

    f32x4 o[2][4] = {};          // O^T: o[ri][dj][e]: row d=dj*16+lg*4+e, col q=ri*16+lr
    float m2[2] = {-INFINITY, -INFINITY};
    float ls[2] = {0.f, 0.f};

    const unsigned short* kb = qkv + qrowbase + 768 + h * 64;     // K cols
    const unsigned short* vt = vtb + (size_t)(b * 12 + h) * 64 * 2048;

    for (int kt = w; kt < nkv; kt += 4) {
        const int kv0 = kt * 64;
        // K fragments (A-operand): K[kv0+cj*16+lr][kk*32+lg*8..]
        bf16x8 kf[4][2];
#pragma unroll
        for (int cj = 0; cj < 4; ++cj)
#pragma unroll
            for (int kk = 0; kk < 2; ++kk)
                kf[cj][kk] = *(const bf16x8*)(kb + (size_t)(kv0 + cj * 16 + lr) * 2304 +
                                              kk * 32 + lg * 8);

        // S^T tiles: st[ri][cj][e] = S[q0+ri*16+lr][kv0+cj*16+lg*4+e]
        f32x4 st[2][4];
        const f32x4 zz = {0.f, 0.f, 0.f, 0.f};
        __builtin_amdgcn_s_setprio(1);
#pragma unroll
        for (int ri = 0; ri < 2; ++ri)
#pragma unroll
            for (int cj = 0; cj < 4; ++cj) {
                f32x4 a0 = __builtin_amdgcn_mfma_f32_16x16x32_bf16(kf[cj][0], qf[ri][0], zz, 0, 0, 0);
                st[ri][cj] = __builtin_amdgcn_mfma_f32_16x16x32_bf16(kf[cj][1], qf[ri][1], a0, 0, 0, 0);
            }
        __builtin_amdgcn_s_setprio(0);

        // V fragments (A-operand for O^T): V^T[dj*16+lr][kv0+kk*32+lg*8..]
        bf16x8 vf[2][4];
#pragma unroll
        for (int kk = 0; kk < 2; ++kk)
#pragma unroll
            for (int dj = 0; dj < 4; ++dj)
                vf[kk][dj] = *(const bf16x8*)(vt + (size_t)(dj * 16 + lr) * 2048 +
                                              kv0 + kk * 32 + lg * 8);

        if (kt == nkv - 1) {  // diagonal tile: mask kv > q
#pragma unroll
            for (int ri = 0; ri < 2; ++ri)
#pragma unroll
                for (int cj = 0; cj < 4; ++cj)
#pragma unroll
                    for (int e = 0; e < 4; ++e) {
                        const int kvv = kv0 + cj * 16 + lg * 4 + e;
                        const int qq  = q0 + ri * 16 + lr;
                        if (kvv > qq) st[ri][cj][e] = -1e30f;
                    }
        }

#pragma unroll
        for (int ri = 0; ri < 2; ++ri) {
            // in-lane max over 16 kv values, then 2 shfl steps over lg-partners
            f32x4 t4;
#pragma unroll
            for (int e = 0; e < 4; ++e)
                t4[e] = fmaxf(fmaxf(st[ri][0][e], st[ri][1][e]),
                              fmaxf(st[ri][2][e], st[ri][3][e]));
            float mx = fmaxf(fmaxf(t4[0], t4[1]), fmaxf(t4[2], t4[3]));
            mx = fmaxf(mx, __shfl_xor(mx, 16));
            mx = fmaxf(mx, __shfl_xor(mx, 32));

            const float m2n = fmaxf(m2[ri], mx);
            const bool grow = (m2n > m2[ri]);
            if (__any(grow)) {
                const float fs = __builtin_amdgcn_exp2f(m2[ri] - m2n);
                ls[ri] *= fs;
#pragma unroll
                for (int dj = 0; dj < 4; ++dj) o[ri][dj] *= fs;
                m2[ri] = m2n;
            }

            float ps = 0.f;
#pragma unroll
            for (int cj = 0; cj < 4; ++cj)
#pragma unroll
                for (int e = 0; e < 4; ++e) {
                    const float p = __builtin_amdgcn_exp2f(st[ri][cj][e] - m2[ri]);
                    st[ri][cj][e] = p;
                    ps += p;
                }
            ps += __shfl_xor(ps, 16);
            ps += __shfl_xor(ps, 32);
            ls[ri] += ps;

            // P store: row q=ri*16+lr, cols kv=cj*16+lg*4..+3 (8 B), granule-XOR swizzle
            const int row = ri * 16 + lr;
#pragma unroll
            for (int cj = 0; cj < 4; ++cj) {
                unsigned lo, hi;
                asm("v_cvt_pk_bf16_f32 %0, %1, %2"
                    : "=v"(lo) : "v"(st[ri][cj][0]), "v"(st[ri][cj][1]));
                asm("v_cvt_pk_bf16_f32 %0, %1, %2"
                    : "=v"(hi) : "v"(st[ri][cj][2]), "v"(st[ri][cj][3]));
                const int gr = (cj * 2 + (lg >> 1)) ^ (lr & 7);
                uint2 pk2; pk2.x = lo; pk2.y = hi;
                *(uint2*)(p_w + row * 128 + gr * 16 + (lg & 1) * 8) = pk2;
            }
        }

        // fence: P-stores above must not be reordered past the pa loads below
        asm volatile("" ::: "memory");

        __builtin_amdgcn_s_setprio(1);
#pragma unroll
        for (int kk = 0; kk < 2; ++kk)
#pragma unroll
            for (int ri = 0; ri < 2; ++ri) {
                const int row = ri * 16 + lr;
                const int g = (kk * 4 + lg) ^ (lr & 7);
                bf16x8 pa = *(const bf16x8*)(p_w + row * 128 + g * 16);
#pragma unroll
                for (int dj = 0; dj < 4; ++dj)
                    o[ri][dj] = __builtin_amdgcn_mfma_f32_16x16x32_bf16(
                        vf[kk][dj], pa, o[ri][dj], 0, 0, 0);
            }
        __builtin_amdgcn_s_setprio(0);

        // fence: next iteration's P-stores must not be hoisted above the pa loads
        asm volatile("" ::: "memory");
    }

    // ---- in-block merge of 4 wave partials ----
    if (lg == 0) {
#pragma unroll
        for (int ri = 0; ri < 2; ++ri) {
            mlds[w * 32 + ri * 16 + lr] = m2[ri];
            llds[w * 32 + ri * 16 + lr] = ls[ri];
        }
    }
    __syncthreads();

    float* o_w = (float*)(smem + w * WREG);  // [32][72] f32, reuses own p region
#pragma unroll
    for (int ri = 0; ri < 2; ++ri) {
        const int row = ri * 16 + lr;
        const float mg = fmaxf(fmaxf(mlds[row], mlds[32 + row]),
                               fmaxf(mlds[64 + row], mlds[96 + row]));
        const float f = __builtin_amdgcn_exp2f(m2[ri] - mg);
#pragma unroll
        for (int dj = 0; dj < 4; ++dj) {
            f32x4 v = o[ri][dj] * f;
            *(f32x4*)&o_w[row * 72 + dj * 16 + lg * 4] = v;
        }
    }
    __syncthreads();

    {
        const int row = w * 8 + (l >> 3);
        const int c0 = (l & 7) * 8;
        const float mg = fmaxf(fmaxf(mlds[row], mlds[32 + row]),
                               fmaxf(mlds[64 + row], mlds[96 + row]));
        float lt = 0.f;
#pragma unroll
        for (int s = 0; s < 4; ++s)
            lt += __builtin_amdgcn_exp2f(mlds[s * 32 + row] - mg) * llds[s * 32 + row];
        const float inv = 1.0f / lt;
        ushort4 pk[2];
#pragma unroll
        for (int half = 0; half < 2; ++half) {
            unsigned short u[4];
#pragma unroll
            for (int k = 0; k < 4; ++k) {
                float acc = 0.f;
#pragma unroll
                for (int s = 0; s < 4; ++s)
                    acc += ((const float*)(smem + s * WREG))[row * 72 + c0 + half * 4 + k];
                u[k] = f32_bf16(acc * inv);
            }
            pk[half] = make_ushort4(u[0], u[1], u[2], u[3]);
        }
        unsigned short* dst = zb + (size_t)(b * 2048 + q0 + row) * 768 + h * 64 + c0;
        *(ushort4*)dst = pk[0];
        *(ushort4*)(dst + 4) = pk[1];
    }
}

extern "C" void kernel_launch(void* const* d_in, const int* in_sizes, int n_in,
                              void* d_out, int out_size, void* d_ws, size_t ws_size,
                              hipStream_t stream) {
    (void)in_sizes; (void)n_in; (void)out_size; (void)ws_size;
    const float* x   = (const float*)d_in[0];
    const float* W_Q = (const float*)d_in[1];
    const float* W_K = (const float*)d_in[2];
    const float* W_V = (const float*)d_in[3];
    const float* b_Q = (const float*)d_in[4];
    const float* b_K = (const float*)d_in[5];
    const float* b_V = (const float*)d_in[6];
    const float* W_O = (const float*)d_in[7];
    const float* b_O = (const float*)d_in[8];
    float* out = (float*)d_out;

    char* ws = (char*)d_ws;
    unsigned short* xb    = (unsigned short*)(ws);
    unsigned short* qkvb  = (unsigned short*)(ws + 6291456);
    unsigned short* vtb   = (unsigned short*)(ws + 25165824);
    unsigned short* wqkvT = (unsigned short*)(ws + 31457280);
    unsigned short* woT   = (unsigned short*)(ws + 34996224);
    unsigned short* zb    = xb;  // xb dead after the QKV GEMM

    k_prep<<<3648, 256, 0, stream>>>(x, W_Q, W_K, W_V, W_O, xb, wqkvT, woT);

    k_gemm<128, 128, true><<<dim3(18, 32), 256, 0, stream>>>(xb, wqkvT, b_Q, b_K, b_V, qkvb, nullptr);

    k_transpose_v<<<dim3(32, 24), 256, 0, stream>>>(qkvb + 1536, vtb);
    k_flash<<<dim3(24, 64), 256, 0, stream>>>(qkvb, vtb, zb);
    k_gemm<64, 64, false><<<dim3(12, 64), 256, 0, stream>>>(zb, woT, b_O, b_O, b_O, nullptr, out);
}

// Round 8
// 113.895 us; speedup vs baseline: 1.8703x; 1.1603x over previous
//
#include <hip/hip_runtime.h>

// Fused causal MHA on gfx950.  Pipeline (R7 = R6 minus the VGPR-capping
// launch_bounds hint — R6's ",4" forced 64 VGPR -> 124 MB scratch spills):
//   k_prep:        x fp32 -> xb bf16 ; W_Q|W_K|W_V -> wqkvT bf16 [2304][768] ;
//                  W_O -> woT bf16 [768][768]^T     (one kernel, 3 job ranges)
//   k_gemm<128,128,true>:  qkvb bf16 [4096][2304] = xb @ wqkvT^T + bias
//                  (Q cols pre-scaled by 0.125*log2e; global_load_lds staging)
//   k_transpose_v: qkvb(v cols) -> vtb [24][64][2048]
//   k_flash:       QBLK=32, 4 waves split KV range, swapped-operand softmax:
//                  QK^T computed as mfma(K,Q)=S^T (q = lane&15), PV as
//                  mfma(V^T,P)=O^T -> scalar m/l per lane, 2-step shfl reduces.
//   k_gemm<64,64,false>:   d_out fp32 = zb @ woT^T + b_O
//
// ws: xb/zb @0 (6291456) | qkvb @6291456 (18874368) | vtb @25165824 (6291456)
//     wqkvT @31457280 (3538944) | woT @34996224 (1179648)   total 36175872 B

#define DEVINL __device__ __forceinline__

using bf16x8 = __attribute__((ext_vector_type(8))) __bf16;
using f32x4  = __attribute__((ext_vector_type(4))) float;

DEVINL unsigned short f32_bf16(float f) {
    unsigned u = __builtin_bit_cast(unsigned, f);
    return (unsigned short)((u + 0x7FFFu + ((u >> 16) & 1u)) >> 16);
}

DEVINL void gload16(const void* g, void* l) {
    __builtin_amdgcn_global_load_lds(
        (const __attribute__((address_space(1))) void*)g,
        (__attribute__((address_space(3))) void*)l, 16, 0, 0);
}

// ---------------- fused prep: convert + weight transposes ----------------
// blocks [0,3072): convert x; [3072,3504): wqkv transpose; [3504,3648): W_O transpose.
__global__ __launch_bounds__(256) void k_prep(const float* __restrict__ x,
                                              const float* __restrict__ Wq,
                                              const float* __restrict__ Wk,
                                              const float* __restrict__ Wv,
                                              const float* __restrict__ Wo,
                                              unsigned short* __restrict__ xb,
                                              unsigned short* __restrict__ wqkvT,
                                              unsigned short* __restrict__ woT) {
    __shared__ unsigned short tl[64][68];
    const int bid = blockIdx.x;
    const int t = threadIdx.x;
    if (bid < 3072) {
        int i = (bid * 256 + t) * 4;
        float4 v = *(const float4*)(x + i);
        ushort4 o;
        o.x = f32_bf16(v.x); o.y = f32_bf16(v.y); o.z = f32_bf16(v.z); o.w = f32_bf16(v.w);
        *(ushort4*)(xb + i) = o;
        return;
    }
    const int c = t & 63, r0 = t >> 6;
    if (bid < 3504) {
        const int sub = bid - 3072;          // 0..431
        const int tr = sub % 12, batch = sub / 12;   // batch 0..35
        const float* src = (batch < 12) ? Wq : (batch < 24) ? Wk : Wv;
        src += (size_t)(batch % 12) * 768 * 64;
        unsigned short* out = wqkvT + (size_t)batch * 64 * 768;
#pragma unroll
        for (int k = 0; k < 16; ++k) {
            int r = k * 4 + r0;
            tl[r][c] = f32_bf16(src[(size_t)(tr * 64 + r) * 64 + c]);
        }
        __syncthreads();
#pragma unroll
        for (int k = 0; k < 16; ++k) {
            int r2 = k * 4 + r0;
            out[(size_t)r2 * 768 + tr * 64 + c] = tl[c][r2];
        }
    } else {
        const int sub = bid - 3504;          // 0..143
        const int tr = sub % 12, tc = sub / 12;
#pragma unroll
        for (int k = 0; k < 16; ++k) {
            int r = k * 4 + r0;
            tl[r][c] = f32_bf16(Wo[(size_t)(tr * 64 + r) * 768 + tc * 64 + c]);
        }
        __syncthreads();
#pragma unroll
        for (int k = 0; k < 16; ++k) {
            int r2 = k * 4 + r0;
            woT[(size_t)(tc * 64 + r2) * 768 + tr * 64 + c] = tl[c][r2];
        }
    }
}

// ---------------- transpose V: qkvb v-cols [b,s,2304] -> vtb [b*12+h][64][2048] -------
__global__ __launch_bounds__(256) void k_transpose_v(const unsigned short* __restrict__ vb,
                                                     unsigned short* __restrict__ vtb) {
    __shared__ unsigned short tl[64][68];
    const int bh = blockIdx.y;
    const int s0 = blockIdx.x * 64;
    const unsigned short* in = vb + ((size_t)((bh / 12) * 2048 + s0)) * 2304 + (bh % 12) * 64;
    unsigned short* outp = vtb + (size_t)bh * 64 * 2048 + s0;
    const int t = threadIdx.x, c = t & 63, r0 = t >> 6;
#pragma unroll
    for (int k = 0; k < 16; ++k) {
        int r = k * 4 + r0;
        tl[r][c] = in[(size_t)r * 2304 + c];
    }
    __syncthreads();
#pragma unroll
    for (int k = 0; k < 16; ++k) {
        int r2 = k * 4 + r0;
        outp[(size_t)r2 * 2048 + c] = tl[c][r2];
    }
}

// ---------------- GEMM: C[4096][N] = A[4096][768] @ BT[N][768] + bias ----------------
// m97 structure: unpadded LDS (64 B rows), global_load_lds width-16 staging,
// 2-barrier loop, 4 waves in 2x2.
template <int BM, int BN, bool QKV>
__global__ __launch_bounds__(256) void k_gemm(const unsigned short* __restrict__ A,
                                              const unsigned short* __restrict__ BT,
                                              const float* __restrict__ b0,
                                              const float* __restrict__ b1,
                                              const float* __restrict__ b2,
                                              unsigned short* __restrict__ outb,
                                              float* __restrict__ outf) {
    constexpr int LDC = QKV ? 2304 : 768;
    constexpr int WM = BM / 2, WN = BN / 2, MR = WM / 16, NR = WN / 16;
    __shared__ alignas(16) unsigned short As[BM * 32];
    __shared__ alignas(16) unsigned short Bs[BN * 32];
    const int t = threadIdx.x;
    const int w = t >> 6, l = t & 63, lr = l & 15, lg = l >> 4;
    const int wr = (w >> 1) * WM, wc = (w & 1) * WN;
    const int m0 = blockIdx.y * BM;
    const int n0 = blockIdx.x * BN;

    f32x4 acc[MR][NR] = {};

    for (int kt = 0; kt < 24; ++kt) {
        const int k0 = kt * 32;
        __syncthreads();
#pragma unroll
        for (int i = 0; i < BM / 64; ++i) {
            const int s = i * 256 + t;
            gload16((const char*)A + ((size_t)(m0 + (s >> 2)) * 768 + k0) * 2 + (s & 3) * 16,
                    (char*)As + s * 16);
        }
#pragma unroll
        for (int i = 0; i < BN / 64; ++i) {
            const int s = i * 256 + t;
            gload16((const char*)BT + ((size_t)(n0 + (s >> 2)) * 768 + k0) * 2 + (s & 3) * 16,
                    (char*)Bs + s * 16);
        }
        __syncthreads();   // drains vmcnt(0): LDS tiles ready

        bf16x8 af[MR], bfr[NR];
#pragma unroll
        for (int ri = 0; ri < MR; ++ri)
            af[ri] = *(const bf16x8*)&As[(wr + ri * 16 + lr) * 32 + lg * 8];
#pragma unroll
        for (int cj = 0; cj < NR; ++cj)
            bfr[cj] = *(const bf16x8*)&Bs[(wc + cj * 16 + lr) * 32 + lg * 8];
        __builtin_amdgcn_s_setprio(1);
#pragma unroll
        for (int ri = 0; ri < MR; ++ri)
#pragma unroll
            for (int cj = 0; cj < NR; ++cj)
                acc[ri][cj] = __builtin_amdgcn_mfma_f32_16x16x32_bf16(
                    af[ri], bfr[cj], acc[ri][cj], 0, 0, 0);
        __builtin_amdgcn_s_setprio(0);
    }

#pragma unroll
    for (int cj = 0; cj < NR; ++cj) {
        const int col = n0 + wc + cj * 16 + lr;
        const float* bp = b0;
        int cc = col;
        if (QKV) {
            if (col >= 1536)      { bp = b2; cc = col - 1536; }
            else if (col >= 768)  { bp = b1; cc = col - 768; }
        }
        const float bv = bp[cc];
        const float scl = (QKV && col < 768) ? 0.18033688011112042f : 1.0f;  // 0.125*log2e
#pragma unroll
        for (int ri = 0; ri < MR; ++ri)
#pragma unroll
            for (int e = 0; e < 4; ++e) {
                const int row = m0 + wr + ri * 16 + lg * 4 + e;
                const float v = (acc[ri][cj][e] + bv) * scl;
                if (QKV) outb[(size_t)row * LDC + col] = f32_bf16(v);
                else     outf[(size_t)row * LDC + col] = v;
            }
    }
}

// ---------------- flash attention, wave-split KV, swapped-operand softmax -------------
// grid (hb=24, qv=64). qi = 63-qv (longest first). Block: 32 q-rows.
// Wave w handles kv tiles w, w+4, ... privately; merge at end via LDS.
// QK^T as mfma(K,Q)=S^T: lane holds 16 kv for fixed q=ri*16+lr -> scalar m/l,
// 15 in-lane fmax + 2 shfl steps.  PV as mfma(V^T,P)=O^T so o's q axis = lr too.
// Per-wave LDS region WREG: P tile [32 q][64 kv] bf16 (4096 B, XOR-swizzled 16B
// granules) during loop; o-merge [32][72] f32 (9216 B) in epilogue.
#define WREG 9216
__global__ __launch_bounds__(256) void k_flash(const unsigned short* __restrict__ qkv,
                                               const unsigned short* __restrict__ vtb,
                                               unsigned short* __restrict__ zb) {
    __shared__ alignas(16) char smem[4 * WREG + 1024];
    const int hb = blockIdx.x;              // 0..23
    const int h = hb % 12, b = hb / 12;
    const int qi = 63 - (int)blockIdx.y;
    const int q0 = qi * 32;
    const int t = threadIdx.x, w = t >> 6, l = t & 63, lr = l & 15, lg = l >> 4;
    const int nkv = (qi >> 1) + 1;

    char* p_w = smem + w * WREG;                      // P[q][kv] bf16, swizzled
    float* mlds = (float*)(smem + 4 * WREG);          // [4][32]
    float* llds = (float*)(smem + 4 * WREG + 512);    // [4][32]

    const size_t qrowbase = (size_t)(b * 2048) * 2304;
    // Q fragments (B-operand now): Q[q0+ri*16+lr][kk*32+lg*8..] (pre-scaled)
    bf16x8 qf[2][2];
#pragma unroll
    for (int ri = 0; ri < 2; ++ri)
#pragma unroll
        for (int kk = 0; kk < 2; ++kk)
            qf[ri][kk] = *(const bf16x8*)(qkv + qrowbase + (size_t)(q0 + ri * 16 + lr) * 2304 +
                                          h * 64 + kk * 32 + lg * 8);

    f32x4 o[2][4] = {};          // O^T: o[ri][dj][e]: row d=dj*16+lg*4+e, col q=ri*16+lr
    float m2[2] = {-INFINITY, -INFINITY};
    float ls[2] = {0.f, 0.f};

    const unsigned short* kb = qkv + qrowbase + 768 + h * 64;     // K cols
    const unsigned short* vt = vtb + (size_t)(b * 12 + h) * 64 * 2048;

    for (int kt = w; kt < nkv; kt += 4) {
        const int kv0 = kt * 64;
        // K fragments (A-operand): K[kv0+cj*16+lr][kk*32+lg*8..]
        bf16x8 kf[4][2];
#pragma unroll
        for (int cj = 0; cj < 4; ++cj)
#pragma unroll
            for (int kk = 0; kk < 2; ++kk)
                kf[cj][kk] = *(const bf16x8*)(kb + (size_t)(kv0 + cj * 16 + lr) * 2304 +
                                              kk * 32 + lg * 8);

        // S^T tiles: st[ri][cj][e] = S[q0+ri*16+lr][kv0+cj*16+lg*4+e]
        f32x4 st[2][4];
        const f32x4 zz = {0.f, 0.f, 0.f, 0.f};
        __builtin_amdgcn_s_setprio(1);
#pragma unroll
        for (int ri = 0; ri < 2; ++ri)
#pragma unroll
            for (int cj = 0; cj < 4; ++cj) {
                f32x4 a0 = __builtin_amdgcn_mfma_f32_16x16x32_bf16(kf[cj][0], qf[ri][0], zz, 0, 0, 0);
                st[ri][cj] = __builtin_amdgcn_mfma_f32_16x16x32_bf16(kf[cj][1], qf[ri][1], a0, 0, 0, 0);
            }
        __builtin_amdgcn_s_setprio(0);

        // V fragments (A-operand for O^T): V^T[dj*16+lr][kv0+kk*32+lg*8..]
        bf16x8 vf[2][4];
#pragma unroll
        for (int kk = 0; kk < 2; ++kk)
#pragma unroll
            for (int dj = 0; dj < 4; ++dj)
                vf[kk][dj] = *(const bf16x8*)(vt + (size_t)(dj * 16 + lr) * 2048 +
                                              kv0 + kk * 32 + lg * 8);

        if (kt == nkv - 1) {  // diagonal tile: mask kv > q
#pragma unroll
            for (int ri = 0; ri < 2; ++ri)
#pragma unroll
                for (int cj = 0; cj < 4; ++cj)
#pragma unroll
                    for (int e = 0; e < 4; ++e) {
                        const int kvv = kv0 + cj * 16 + lg * 4 + e;
                        const int qq  = q0 + ri * 16 + lr;
                        if (kvv > qq) st[ri][cj][e] = -1e30f;
                    }
        }

#pragma unroll
        for (int ri = 0; ri < 2; ++ri) {
            // in-lane max over 16 kv values, then 2 shfl steps over lg-partners
            f32x4 t4;
#pragma unroll
            for (int e = 0; e < 4; ++e)
                t4[e] = fmaxf(fmaxf(st[ri][0][e], st[ri][1][e]),
                              fmaxf(st[ri][2][e], st[ri][3][e]));
            float mx = fmaxf(fmaxf(t4[0], t4[1]), fmaxf(t4[2], t4[3]));
            mx = fmaxf(mx, __shfl_xor(mx, 16));
            mx = fmaxf(mx, __shfl_xor(mx, 32));

            const float m2n = fmaxf(m2[ri], mx);
            const bool grow = (m2n > m2[ri]);
            if (__any(grow)) {
                const float fs = __builtin_amdgcn_exp2f(m2[ri] - m2n);
                ls[ri] *= fs;
#pragma unroll
                for (int dj = 0; dj < 4; ++dj) o[ri][dj] *= fs;
                m2[ri] = m2n;
            }

            float ps = 0.f;
#pragma unroll
            for (int cj = 0; cj < 4; ++cj)
#pragma unroll
                for (int e = 0; e < 4; ++e) {
                    const float p = __builtin_amdgcn_exp2f(st[ri][cj][e] - m2[ri]);
                    st[ri][cj][e] = p;
                    ps += p;
                }
            ps += __shfl_xor(ps, 16);
            ps += __shfl_xor(ps, 32);
            ls[ri] += ps;

            // P store: row q=ri*16+lr, cols kv=cj*16+lg*4..+3 (8 B), granule-XOR swizzle
            const int row = ri * 16 + lr;
#pragma unroll
            for (int cj = 0; cj < 4; ++cj) {
                unsigned lo, hi;
                asm("v_cvt_pk_bf16_f32 %0, %1, %2"
                    : "=v"(lo) : "v"(st[ri][cj][0]), "v"(st[ri][cj][1]));
                asm("v_cvt_pk_bf16_f32 %0, %1, %2"
                    : "=v"(hi) : "v"(st[ri][cj][2]), "v"(st[ri][cj][3]));
                const int gr = (cj * 2 + (lg >> 1)) ^ (lr & 7);
                uint2 pk2; pk2.x = lo; pk2.y = hi;
                *(uint2*)(p_w + row * 128 + gr * 16 + (lg & 1) * 8) = pk2;
            }
        }

        // fence: P-stores above must not be reordered past the pa loads below
        asm volatile("" ::: "memory");

        __builtin_amdgcn_s_setprio(1);
#pragma unroll
        for (int kk = 0; kk < 2; ++kk)
#pragma unroll
            for (int ri = 0; ri < 2; ++ri) {
                const int row = ri * 16 + lr;
                const int g = (kk * 4 + lg) ^ (lr & 7);
                bf16x8 pa = *(const bf16x8*)(p_w + row * 128 + g * 16);
#pragma unroll
                for (int dj = 0; dj < 4; ++dj)
                    o[ri][dj] = __builtin_amdgcn_mfma_f32_16x16x32_bf16(
                        vf[kk][dj], pa, o[ri][dj], 0, 0, 0);
            }
        __builtin_amdgcn_s_setprio(0);

        // fence: next iteration's P-stores must not be hoisted above the pa loads
        asm volatile("" ::: "memory");
    }

    // ---- in-block merge of 4 wave partials ----
    if (lg == 0) {
#pragma unroll
        for (int ri = 0; ri < 2; ++ri) {
            mlds[w * 32 + ri * 16 + lr] = m2[ri];
            llds[w * 32 + ri * 16 + lr] = ls[ri];
        }
    }
    __syncthreads();

    float* o_w = (float*)(smem + w * WREG);  // [32][72] f32, reuses own p region
#pragma unroll
    for (int ri = 0; ri < 2; ++ri) {
        const int row = ri * 16 + lr;
        const float mg = fmaxf(fmaxf(mlds[row], mlds[32 + row]),
                               fmaxf(mlds[64 + row], mlds[96 + row]));
        const float f = __builtin_amdgcn_exp2f(m2[ri] - mg);
#pragma unroll
        for (int dj = 0; dj < 4; ++dj) {
            f32x4 v = o[ri][dj] * f;
            *(f32x4*)&o_w[row * 72 + dj * 16 + lg * 4] = v;
        }
    }
    __syncthreads();

    {
        const int row = w * 8 + (l >> 3);
        const int c0 = (l & 7) * 8;
        const float mg = fmaxf(fmaxf(mlds[row], mlds[32 + row]),
                               fmaxf(mlds[64 + row], mlds[96 + row]));
        float lt = 0.f;
#pragma unroll
        for (int s = 0; s < 4; ++s)
            lt += __builtin_amdgcn_exp2f(mlds[s * 32 + row] - mg) * llds[s * 32 + row];
        const float inv = 1.0f / lt;
        ushort4 pk[2];
#pragma unroll
        for (int half = 0; half < 2; ++half) {
            unsigned short u[4];
#pragma unroll
            for (int k = 0; k < 4; ++k) {
                float acc = 0.f;
#pragma unroll
                for (int s = 0; s < 4; ++s)
                    acc += ((const float*)(smem + s * WREG))[row * 72 + c0 + half * 4 + k];
                u[k] = f32_bf16(acc * inv);
            }
            pk[half] = make_ushort4(u[0], u[1], u[2], u[3]);
        }
        unsigned short* dst = zb + (size_t)(b * 2048 + q0 + row) * 768 + h * 64 + c0;
        *(ushort4*)dst = pk[0];
        *(ushort4*)(dst + 4) = pk[1];
    }
}

extern "C" void kernel_launch(void* const* d_in, const int* in_sizes, int n_in,
                              void* d_out, int out_size, void* d_ws, size_t ws_size,
                              hipStream_t stream) {
    (void)in_sizes; (void)n_in; (void)out_size; (void)ws_size;
    const float* x   = (const float*)d_in[0];
    const float* W_Q = (const float*)d_in[1];
    const float* W_K = (const float*)d_in[2];
    const float* W_V = (const float*)d_in[3];
    const float* b_Q = (const float*)d_in[4];
    const float* b_K = (const float*)d_in[5];
    const float* b_V = (const float*)d_in[6];
    const float* W_O = (const float*)d_in[7];
    const float* b_O = (const float*)d_in[8];
    float* out = (float*)d_out;

    char* ws = (char*)d_ws;
    unsigned short* xb    = (unsigned short*)(ws);
    unsigned short* qkvb  = (unsigned short*)(ws + 6291456);
    unsigned short* vtb   = (unsigned short*)(ws + 25165824);
    unsigned short* wqkvT = (unsigned short*)(ws + 31457280);
    unsigned short* woT   = (unsigned short*)(ws + 34996224);
    unsigned short* zb    = xb;  // xb dead after the QKV GEMM

    k_prep<<<3648, 256, 0, stream>>>(x, W_Q, W_K, W_V, W_O, xb, wqkvT, woT);

    k_gemm<128, 128, true><<<dim3(18, 32), 256, 0, stream>>>(xb, wqkvT, b_Q, b_K, b_V, qkvb, nullptr);

    k_transpose_v<<<dim3(32, 24), 256, 0, stream>>>(qkvb + 1536, vtb);
    k_flash<<<dim3(24, 64), 256, 0, stream>>>(qkvb, vtb, zb);
    k_gemm<64, 64, false><<<dim3(12, 64), 256, 0, stream>>>(zb, woT, b_O, b_O, b_O, nullptr, out);
}